// Round 7
// baseline (614.415 us; speedup 1.0000x reference)
//
#include <hip/hip_runtime.h>
#include <hip/hip_bf16.h>
#include <math.h>

// ---------------------------------------------------------------------------
// GAT 3-layer forward.
//  - GEMMs: split-bf16 (bf16x3) on MFMA pipe; C written as fp16 feat table.
//    128x128 tiles; XOR-swizzled LDS (proven 0 conflicts); DOUBLE-BUFFERED
//    with ONE barrier per K-step: top-of-step {vmcnt(0)+lgkmcnt(0)+barrier}
//    waits on staging issued a full phase earlier (nearly free), then frag
//    reads, then stage kt+1 (SPLITA float4 A first, gl_lds B after -> cvt's
//    compiler wait is vmcnt(4), B stays in flight), MFMA, cvt+ds_write late.
//    Fixes R5's FIFO bug (vmcnt(8) was draining kt+1's HBM A-loads).
//    elr (el/er attention dots) fused into the GEMM epilogue.
//  - agg: wave-per-node, SINGLE pass (deferred softmax normalization).
// ---------------------------------------------------------------------------

#define HID 256

typedef __attribute__((ext_vector_type(8))) __bf16 bf16x8;
typedef __attribute__((ext_vector_type(4))) __bf16 bf16x4;
typedef __attribute__((ext_vector_type(8))) _Float16 half8;
typedef __attribute__((ext_vector_type(4))) _Float16 half4;
typedef __attribute__((ext_vector_type(4))) float floatx4;

__device__ __forceinline__ void gl_lds16(const void* g, void* l) {
    __builtin_amdgcn_global_load_lds(
        (const __attribute__((address_space(1))) void*)g,
        (__attribute__((address_space(3))) void*)l, 16, 0, 0);
}

// ---------------- CSR build ----------------

__global__ void hist_kernel(const int* __restrict__ dst, int* __restrict__ cnt, int E) {
    int e = blockIdx.x * blockDim.x + threadIdx.x;
    if (e < E) atomicAdd(&cnt[dst[e]], 1);
}

__global__ __launch_bounds__(256) void scan1_kernel(const int* __restrict__ cnt,
                                                    int* __restrict__ bsum, int n) {
    __shared__ int w[4];
    int t = threadIdx.x;
    int i = blockIdx.x * 256 + t;
    int c = (i < n) ? cnt[i] : 0;
    int acc = c;
#pragma unroll
    for (int off = 32; off > 0; off >>= 1) acc += __shfl_xor(acc, off);
    if ((t & 63) == 0) w[t >> 6] = acc;
    __syncthreads();
    if (t == 0) bsum[blockIdx.x] = w[0] + w[1] + w[2] + w[3];
}

__global__ __launch_bounds__(256) void scan2_kernel(const int* __restrict__ bsum,
                                                    int* __restrict__ boff, int nb) {
    __shared__ int buf[256];
    int t = threadIdx.x;
    int v = (t < nb) ? bsum[t] : 0;
    buf[t] = v;
    __syncthreads();
    for (int off = 1; off < 256; off <<= 1) {
        int x = (t >= off) ? buf[t - off] : 0;
        __syncthreads();
        buf[t] += x;
        __syncthreads();
    }
    if (t < nb) boff[t] = buf[t] - v;
}

__global__ __launch_bounds__(256) void scan3_kernel(const int* __restrict__ cnt,
                                                    const int* __restrict__ boff,
                                                    int* __restrict__ rowptr,
                                                    int* __restrict__ cursor, int n) {
    __shared__ int buf[256];
    int t = threadIdx.x;
    int i = blockIdx.x * 256 + t;
    int c = (i < n) ? cnt[i] : 0;
    buf[t] = c;
    __syncthreads();
    for (int off = 1; off < 256; off <<= 1) {
        int x = (t >= off) ? buf[t - off] : 0;
        __syncthreads();
        buf[t] += x;
        __syncthreads();
    }
    int start = boff[blockIdx.x] + buf[t] - c;
    if (i < n) {
        rowptr[i] = start;
        cursor[i] = start;
        if (i == n - 1) rowptr[n] = start + c;
    }
}

__global__ void fill_kernel(const int* __restrict__ src, const int* __restrict__ dst,
                            int* __restrict__ cursor, int* __restrict__ adj, int E) {
    int e = blockIdx.x * blockDim.x + threadIdx.x;
    if (e < E) {
        int d = dst[e];
        int pos = atomicAdd(&cursor[d], 1);
        adj[pos] = src[e];
    }
}

// ---------------- all weight matrices -> transposed bf16 hi/lo --------------

__device__ __forceinline__ void splitT_one(const float* W, __bf16* ht, __bf16* lt,
                                           int idx, int K) {
    int k = idx >> 8, n = idx & 255;  // Nn == 256
    float v = W[idx];
    __bf16 h = (__bf16)v;
    ht[(size_t)n * K + k] = h;
    lt[(size_t)n * K + k] = (__bf16)(v - (float)h);
}

__global__ __launch_bounds__(256) void splitT_all_kernel(
    const float* __restrict__ W0, const float* __restrict__ W1,
    const float* __restrict__ W2, __bf16* h0, __bf16* l0, __bf16* h1,
    __bf16* l1, __bf16* h2, __bf16* l2) {
    int i = blockIdx.x * 256 + threadIdx.x;
    const int n0 = 512 * 256, n1 = 256 * 256;
    if (i < n0) splitT_one(W0, h0, l0, i, 512);
    else if (i < n0 + n1) splitT_one(W1, h1, l1, i - n0, 256);
    else if (i < n0 + 2 * n1) splitT_one(W2, h2, l2, i - n0 - n1, 256);
}

// ---------------- MFMA GEMM + fused elr ----------------
// C[M,256](fp16) = (Ah+Al)@(Bh+Bl);  el/er[row,h] = C_row . al/ar (fp32 acc).
// SPLITA: A is fp32, split to bf16 hi/lo in registers (issue-early/write-late).
// LDS tile layout: [128 rows][4 slots x 16B]; lds_slot = gslot ^ ((row>>1)&3).
// Double-buffered, ONE barrier per K-step, correct FIFO vmcnt accounting.

template <bool SPLITA>
__global__ __launch_bounds__(256, 2) void gemm_mfma_kernel(
    const float* __restrict__ Af, const __bf16* __restrict__ Ah,
    const __bf16* __restrict__ Al, const __bf16* __restrict__ Bht,
    const __bf16* __restrict__ Blt, _Float16* __restrict__ C,
    const float* __restrict__ al, const float* __restrict__ ar,
    float* __restrict__ el, float* __restrict__ er, int M, int K, int H) {
    __shared__ __bf16 sAh[2][4096];
    __shared__ __bf16 sAl[2][4096];
    __shared__ __bf16 sBh[2][4096];
    __shared__ __bf16 sBl[2][4096];

    int t = threadIdx.x;
    int wave = t >> 6, lane = t & 63;
    int wr = wave >> 1, wc = wave & 1;
    int quad = lane >> 4, m16 = lane & 15;

    int rowA0 = blockIdx.y * 128;
    int rowB0 = blockIdx.x * 128;

    // gl_lds staging coords: thread t -> LDS linear chunk t*16B
    // = (row t>>2, lds_slot t&3); load global slot (t&3)^((t>>3)&3).
    int sr = t >> 2;
    int ke = ((t & 3) ^ ((t >> 3) & 3)) * 8;  // swizzled global k-chunk (elems)
    int ldso = t * 8;
    // SPLITA reg-staging coords: thread t -> row t>>1, cols kb..kb+15
    int srow = t >> 1;
    int kb = (t & 1) * 16;
    int s0 = (t & 1) * 2;
    int ssw = (srow >> 1) & 3;
    int soA = srow * 32 + (s0 ^ ssw) * 8;        // slot for cols kb..kb+7
    int soB = srow * 32 + ((s0 + 1) ^ ssw) * 8;  // slot for cols kb+8..kb+15

    size_t ar0 = 0, ar1 = 0, af0 = 0;
    if (SPLITA) {
        af0 = (size_t)min(rowA0 + srow, M - 1) * K + kb;
    } else {
        ar0 = (size_t)min(rowA0 + sr, M - 1) * K;
        ar1 = (size_t)min(rowA0 + sr + 64, M - 1) * K;
    }
    size_t br0 = (size_t)(rowB0 + sr) * K;
    size_t br1 = (size_t)(rowB0 + sr + 64) * K;

    // per-lane swizzled fragment slot offset (elems): quad ^ ((m16>>1)&3)
    int qsw = (quad ^ ((m16 >> 1) & 3)) * 8;

    floatx4 acc[4][4];
    floatx4 z = {0.f, 0.f, 0.f, 0.f};
#pragma unroll
    for (int i = 0; i < 4; i++)
#pragma unroll
        for (int j = 0; j < 4; j++) acc[i][j] = z;

    int nk = K >> 5;

    // ---- prologue: stage tile 0 into buffer 0 ----
    {
        if (SPLITA) {
            const float* ap = Af + af0;
            float4 p0 = ((const float4*)ap)[0];
            float4 p1 = ((const float4*)ap)[1];
            float4 p2 = ((const float4*)ap)[2];
            float4 p3 = ((const float4*)ap)[3];
            gl_lds16(Bht + br0 + ke, &sBh[0][ldso]);
            gl_lds16(Bht + br1 + ke, &sBh[0][2048 + ldso]);
            gl_lds16(Blt + br0 + ke, &sBl[0][ldso]);
            gl_lds16(Blt + br1 + ke, &sBl[0][2048 + ldso]);
            float vv[16] = {p0.x, p0.y, p0.z, p0.w, p1.x, p1.y, p1.z, p1.w,
                            p2.x, p2.y, p2.z, p2.w, p3.x, p3.y, p3.z, p3.w};
            bf16x8 h0, h1, l0, l1;
#pragma unroll
            for (int c = 0; c < 8; c++) {
                __bf16 hv = (__bf16)vv[c];
                h0[c] = hv;
                l0[c] = (__bf16)(vv[c] - (float)hv);
                __bf16 hv2 = (__bf16)vv[8 + c];
                h1[c] = hv2;
                l1[c] = (__bf16)(vv[8 + c] - (float)hv2);
            }
            *(bf16x8*)&sAh[0][soA] = h0;
            *(bf16x8*)&sAh[0][soB] = h1;
            *(bf16x8*)&sAl[0][soA] = l0;
            *(bf16x8*)&sAl[0][soB] = l1;
        } else {
            gl_lds16(Bht + br0 + ke, &sBh[0][ldso]);
            gl_lds16(Bht + br1 + ke, &sBh[0][2048 + ldso]);
            gl_lds16(Blt + br0 + ke, &sBl[0][ldso]);
            gl_lds16(Blt + br1 + ke, &sBl[0][2048 + ldso]);
            gl_lds16(Ah + ar0 + ke, &sAh[0][ldso]);
            gl_lds16(Ah + ar1 + ke, &sAh[0][2048 + ldso]);
            gl_lds16(Al + ar0 + ke, &sAl[0][ldso]);
            gl_lds16(Al + ar1 + ke, &sAl[0][2048 + ldso]);
        }
    }

    int cur = 0;
    for (int kt = 0; kt < nk; kt++) {
        int nxt = cur ^ 1;
        bool have = (kt + 1 < nk);

        // ---- top-of-step sync: staging for 'cur' was issued a full phase
        // ago (prologue or previous iteration) -> these waits are ~free ----
        asm volatile("s_waitcnt vmcnt(0)" ::: "memory");
        asm volatile("s_waitcnt lgkmcnt(0)" ::: "memory");
        __builtin_amdgcn_s_barrier();

        // ---- fragment reads from buf cur (swizzled) ----
        bf16x8 fah[4], fal[4], fbh[4], fbl[4];
#pragma unroll
        for (int i = 0; i < 4; i++) {
            int off = (wr * 64 + i * 16 + m16) * 32 + qsw;
            fah[i] = *(const bf16x8*)&sAh[cur][off];
            fal[i] = *(const bf16x8*)&sAl[cur][off];
        }
#pragma unroll
        for (int j = 0; j < 4; j++) {
            int off = (wc * 64 + j * 16 + m16) * 32 + qsw;
            fbh[j] = *(const bf16x8*)&sBh[cur][off];
            fbl[j] = *(const bf16x8*)&sBl[cur][off];
        }

        // ---- issue next tile's staging (A float4 FIRST, then gl_lds B:
        // the cvt's compiler wait then leaves the gl_lds in flight) ----
        float4 q0, q1, q2, q3;
        if (have) {
            int k1 = (kt + 1) << 5;
            if (SPLITA) {
                const float* ap = Af + af0 + k1;
                q0 = ((const float4*)ap)[0];
                q1 = ((const float4*)ap)[1];
                q2 = ((const float4*)ap)[2];
                q3 = ((const float4*)ap)[3];
            }
            int k0s = k1 + ke;
            gl_lds16(Bht + br0 + k0s, &sBh[nxt][ldso]);
            gl_lds16(Bht + br1 + k0s, &sBh[nxt][2048 + ldso]);
            gl_lds16(Blt + br0 + k0s, &sBl[nxt][ldso]);
            gl_lds16(Blt + br1 + k0s, &sBl[nxt][2048 + ldso]);
            if (!SPLITA) {
                gl_lds16(Ah + ar0 + k0s, &sAh[nxt][ldso]);
                gl_lds16(Ah + ar1 + k0s, &sAh[nxt][2048 + ldso]);
                gl_lds16(Al + ar0 + k0s, &sAl[nxt][ldso]);
                gl_lds16(Al + ar1 + k0s, &sAl[nxt][2048 + ldso]);
            }
        }

        // ---- MFMA (covers staging latency) ----
#pragma unroll
        for (int i = 0; i < 4; i++)
#pragma unroll
            for (int j = 0; j < 4; j++) {
                acc[i][j] = __builtin_amdgcn_mfma_f32_16x16x32_bf16(fah[i], fbh[j], acc[i][j], 0, 0, 0);
                acc[i][j] = __builtin_amdgcn_mfma_f32_16x16x32_bf16(fah[i], fbl[j], acc[i][j], 0, 0, 0);
                acc[i][j] = __builtin_amdgcn_mfma_f32_16x16x32_bf16(fal[i], fbh[j], acc[i][j], 0, 0, 0);
            }

        // ---- SPLITA write-late: cvt + swizzled ds_write into buf nxt ----
        if (SPLITA && have) {
            float vv[16] = {q0.x, q0.y, q0.z, q0.w, q1.x, q1.y, q1.z, q1.w,
                            q2.x, q2.y, q2.z, q2.w, q3.x, q3.y, q3.z, q3.w};
            bf16x8 h0, h1, l0, l1;
#pragma unroll
            for (int c = 0; c < 8; c++) {
                __bf16 hv = (__bf16)vv[c];
                h0[c] = hv;
                l0[c] = (__bf16)(vv[c] - (float)hv);
                __bf16 hv2 = (__bf16)vv[8 + c];
                h1[c] = hv2;
                l1[c] = (__bf16)(vv[8 + c] - (float)hv2);
            }
            *(bf16x8*)&sAh[nxt][soA] = h0;
            *(bf16x8*)&sAh[nxt][soB] = h1;
            *(bf16x8*)&sAl[nxt][soA] = l0;
            *(bf16x8*)&sAl[nxt][soB] = l1;
        }
        cur = nxt;
    }

    // C store (C/D layout: col = m16, row = quad*4 + reg)
#pragma unroll
    for (int i = 0; i < 4; i++) {
        int rowb = rowA0 + wr * 64 + i * 16 + quad * 4;
#pragma unroll
        for (int j = 0; j < 4; j++) {
            int col = rowB0 + wc * 64 + j * 16 + m16;
#pragma unroll
            for (int r = 0; r < 4; r++) {
                int row = rowb + r;
                if (row < M) C[(size_t)row * HID + col] = (_Float16)acc[i][j][r];
            }
        }
    }

    // fused elr: per-row dot with al/ar over this wave's 64-col head chunk
    float alv[4], arv[4];
#pragma unroll
    for (int j = 0; j < 4; j++) {
        int col = rowB0 + wc * 64 + j * 16 + m16;
        alv[j] = al[col];
        arv[j] = ar[col];
    }
    int h = ((rowB0 + wc * 64) >> 6) & (H - 1);
#pragma unroll
    for (int i = 0; i < 4; i++) {
        int rowb = rowA0 + wr * 64 + i * 16 + quad * 4;
#pragma unroll
        for (int r = 0; r < 4; r++) {
            float pe = acc[i][0][r] * alv[0] + acc[i][1][r] * alv[1] +
                       acc[i][2][r] * alv[2] + acc[i][3][r] * alv[3];
            float pr = acc[i][0][r] * arv[0] + acc[i][1][r] * arv[1] +
                       acc[i][2][r] * arv[2] + acc[i][3][r] * arv[3];
#pragma unroll
            for (int off = 1; off < 16; off <<= 1) {
                pe += __shfl_xor(pe, off);
                pr += __shfl_xor(pr, off);
            }
            int row = rowb + r;
            if (m16 == 0 && row < M) {
                if (H == 4) {
                    el[row * 4 + h] = pe;
                    er[row * 4 + h] = pr;
                } else {
                    atomicAdd(&el[row], pe);
                    atomicAdd(&er[row], pr);
                }
            }
        }
    }
}

// ---------------- fp32 GEMM fallback (writes fp16 feat) ----------------

__global__ __launch_bounds__(256) void gemm_kernel(const float* __restrict__ A,
                                                   const float* __restrict__ B,
                                                   _Float16* __restrict__ C,
                                                   int M, int K, int Nn) {
    __shared__ float As[16][128];
    __shared__ float Bs[16][128];

    int t = threadIdx.x;
    int tx = t & 15, ty = t >> 4;
    int arow = t >> 1;
    int acol = (t & 1) * 8;
    int brow = t >> 4;
    int bcol = (t & 15) * 8;

    int gArow = blockIdx.y * 128 + arow;
    const float* aPtr = A + (size_t)gArow * K + acol;
    const float* bPtr = B + (size_t)brow * Nn + blockIdx.x * 128 + bcol;

    float acc[8][8];
#pragma unroll
    for (int i = 0; i < 8; i++)
#pragma unroll
        for (int j = 0; j < 8; j++) acc[i][j] = 0.f;

    bool aok = (gArow < M);
    int nk = K >> 4;
    for (int kt = 0; kt < nk; kt++) {
        int k0 = kt << 4;
        float4 av0 = make_float4(0.f, 0.f, 0.f, 0.f), av1 = av0;
        if (aok) {
            av0 = *(const float4*)(aPtr + k0);
            av1 = *(const float4*)(aPtr + k0 + 4);
        }
        float4 bv0 = *(const float4*)(bPtr + (size_t)k0 * Nn);
        float4 bv1 = *(const float4*)(bPtr + (size_t)k0 * Nn + 4);

        As[acol + 0][arow] = av0.x;
        As[acol + 1][arow] = av0.y;
        As[acol + 2][arow] = av0.z;
        As[acol + 3][arow] = av0.w;
        As[acol + 4][arow] = av1.x;
        As[acol + 5][arow] = av1.y;
        As[acol + 6][arow] = av1.z;
        As[acol + 7][arow] = av1.w;
        *(float4*)&Bs[brow][bcol] = bv0;
        *(float4*)&Bs[brow][bcol + 4] = bv1;
        __syncthreads();

#pragma unroll
        for (int kk = 0; kk < 16; kk++) {
            float4 a0 = *(const float4*)&As[kk][ty * 4];
            float4 a1 = *(const float4*)&As[kk][64 + ty * 4];
            float4 b0 = *(const float4*)&Bs[kk][tx * 4];
            float4 b1 = *(const float4*)&Bs[kk][64 + tx * 4];
            float a[8] = {a0.x, a0.y, a0.z, a0.w, a1.x, a1.y, a1.z, a1.w};
            float b[8] = {b0.x, b0.y, b0.z, b0.w, b1.x, b1.y, b1.z, b1.w};
#pragma unroll
            for (int i = 0; i < 8; i++)
#pragma unroll
                for (int j = 0; j < 8; j++) acc[i][j] = fmaf(a[i], b[j], acc[i][j]);
        }
        __syncthreads();
    }

    int c0 = blockIdx.x * 128 + tx * 4;
#pragma unroll
    for (int half = 0; half < 2; half++) {
#pragma unroll
        for (int i = 0; i < 4; i++) {
            int r = blockIdx.y * 128 + half * 64 + ty * 4 + i;
            if (r < M) {
                _Float16* cp = C + (size_t)r * Nn + c0;
                int ai = half * 4 + i;
#pragma unroll
                for (int j = 0; j < 4; j++) {
                    cp[j] = (_Float16)acc[ai][j];
                    cp[64 + j] = (_Float16)acc[ai][4 + j];
                }
            }
        }
    }
}

// ---------------- el/er (fallback path only) ----------------

__global__ __launch_bounds__(256) void elr_kernel(const _Float16* __restrict__ feat,
                                                  const float* __restrict__ al,
                                                  const float* __restrict__ ar,
                                                  float* __restrict__ el,
                                                  float* __restrict__ er, int H) {
    int n = blockIdx.x, t = threadIdx.x;
    float f = (float)feat[(size_t)n * HID + t];
    float a = f * al[t];
    float b = f * ar[t];
#pragma unroll
    for (int off = 32; off > 0; off >>= 1) {
        a += __shfl_xor(a, off);
        b += __shfl_xor(b, off);
    }
    __shared__ float pa[4], pb[4];
    int wave = t >> 6, lane = t & 63;
    if (lane == 0) { pa[wave] = a; pb[wave] = b; }
    __syncthreads();
    if (H == 4) {
        if (t < 4) {
            el[n * 4 + t] = pa[t];
            er[n * 4 + t] = pb[t];
        }
    } else {
        if (t == 0) {
            el[n] = pa[0] + pa[1] + pa[2] + pa[3];
            er[n] = pb[0] + pb[1] + pb[2] + pb[3];
        }
    }
}

// ---------------- agg: wave-per-node, SINGLE pass, deferred softmax norm ----
// msg = (sum_e ex_e * feat[u_e]) / (sum_e ex_e), ex = exp(lrelu(el[u]+er[v])).
// Both sums accumulated in one sweep over the adjacency; divide at the end.

template <int H, bool RELU, bool WF32, bool WSPLIT>
__global__ __launch_bounds__(256) void agg_tpl(
    const _Float16* __restrict__ feat, const float* __restrict__ el,
    const float* __restrict__ er, const int* __restrict__ rowptr,
    const int* __restrict__ adj, const float* __restrict__ bias,
    float* __restrict__ outf, __bf16* __restrict__ oh, __bf16* __restrict__ ol,
    int N) {
    int wave = threadIdx.x >> 6, lane = threadIdx.x & 63;
    int v = blockIdx.x * 4 + wave;
    if (v >= N) return;
    int row0 = rowptr[v];
    int deg = rowptr[v + 1] - row0;

    int l32 = lane & 31;
    int half = lane >> 5;
    int hd = (H == 4) ? (l32 >> 3) : 0;
    int d0 = l32 * 8;

    float o[8];
    if (deg > 0) {
        float er_h = (H == 4) ? er[v * 4 + hd] : er[v];
        const int* adjr = adj + row0;

        float a[8];
#pragma unroll
        for (int j = 0; j < 8; j++) a[j] = 0.f;
        float sl = 0.f;

        int e = 0;
        // 16 edges per iteration (8 per half-wave)
        for (; e + 16 <= deg; e += 16) {
            int u[8];
            half8 f[8];
            float elv[8];
#pragma unroll
            for (int q = 0; q < 8; q++) u[q] = adjr[e + q * 2 + half];
#pragma unroll
            for (int q = 0; q < 8; q++)
                f[q] = *(const half8*)&feat[(size_t)u[q] * HID + d0];
#pragma unroll
            for (int q = 0; q < 8; q++)
                elv[q] = (H == 4) ? el[u[q] * 4 + hd] : el[u[q]];
#pragma unroll
            for (int q = 0; q < 8; q++) {
                float sc = elv[q] + er_h;
                sc = (sc > 0.f) ? sc : 0.2f * sc;
                float ex = __expf(sc);
                sl += ex;
#pragma unroll
                for (int j = 0; j < 8; j++) a[j] = fmaf(ex, (float)f[q][j], a[j]);
            }
        }
        // 8 edges per iteration
        for (; e + 8 <= deg; e += 8) {
            int u[4];
            half8 f[4];
            float elv[4];
#pragma unroll
            for (int q = 0; q < 4; q++) u[q] = adjr[e + q * 2 + half];
#pragma unroll
            for (int q = 0; q < 4; q++)
                f[q] = *(const half8*)&feat[(size_t)u[q] * HID + d0];
#pragma unroll
            for (int q = 0; q < 4; q++)
                elv[q] = (H == 4) ? el[u[q] * 4 + hd] : el[u[q]];
#pragma unroll
            for (int q = 0; q < 4; q++) {
                float sc = elv[q] + er_h;
                sc = (sc > 0.f) ? sc : 0.2f * sc;
                float ex = __expf(sc);
                sl += ex;
#pragma unroll
                for (int j = 0; j < 8; j++) a[j] = fmaf(ex, (float)f[q][j], a[j]);
            }
        }
        // tail: 2 edges, predicated
        for (; e < deg; e += 2) {
            int ee = e + half;
            bool act = ee < deg;
            int es = act ? ee : (deg - 1);
            int u = adjr[es];
            float elvq = (H == 4) ? el[u * 4 + hd] : el[u];
            half8 f = *(const half8*)&feat[(size_t)u * HID + d0];
            float sc = elvq + er_h;
            sc = (sc > 0.f) ? sc : 0.2f * sc;
            float ex = act ? __expf(sc) : 0.f;
            sl += ex;
#pragma unroll
            for (int j = 0; j < 8; j++) a[j] = fmaf(ex, (float)f[j], a[j]);
        }

        // merge halves (each half holds partial msg + partial ex-sum)
#pragma unroll
        for (int j = 0; j < 8; j++) a[j] += __shfl_xor(a[j], 32);
        sl += __shfl_xor(sl, 32);
        float inv = 1.f / sl;

#pragma unroll
        for (int j = 0; j < 8; j++) {
            o[j] = fmaf(a[j], inv, bias[d0 + j]);
            if (RELU) o[j] = fmaxf(o[j], 0.f);
        }
    } else {
#pragma unroll
        for (int j = 0; j < 8; j++) {
            o[j] = bias[d0 + j];
            if (RELU) o[j] = fmaxf(o[j], 0.f);
        }
    }

    if (half == 0) {
        size_t base = (size_t)v * HID + d0;
        if (WF32) {
            *(float4*)&outf[base] = make_float4(o[0], o[1], o[2], o[3]);
            *(float4*)&outf[base + 4] = make_float4(o[4], o[5], o[6], o[7]);
        }
        if (WSPLIT) {
            bf16x8 hh, ll;
#pragma unroll
            for (int j = 0; j < 8; j++) {
                __bf16 hv = (__bf16)o[j];
                hh[j] = hv;
                ll[j] = (__bf16)(o[j] - (float)hv);
            }
            *(bf16x8*)&oh[base] = hh;
            *(bf16x8*)&ol[base] = ll;
        }
    }
}

// ---------------- launch ----------------

extern "C" void kernel_launch(void* const* d_in, const int* in_sizes, int n_in,
                              void* d_out, int out_size, void* d_ws, size_t ws_size,
                              hipStream_t stream) {
    const float* feats = (const float*)d_in[0];
    const int* src = (const int*)d_in[1];
    const int* dst = (const int*)d_in[2];
    const float* W0 = (const float*)d_in[3];
    const float* al0 = (const float*)d_in[4];
    const float* ar0 = (const float*)d_in[5];
    const float* b0 = (const float*)d_in[6];
    const float* W1 = (const float*)d_in[7];
    const float* al1 = (const float*)d_in[8];
    const float* ar1 = (const float*)d_in[9];
    const float* b1 = (const float*)d_in[10];
    const float* W2 = (const float*)d_in[11];
    const float* al2 = (const float*)d_in[12];
    const float* ar2 = (const float*)d_in[13];
    const float* b2 = (const float*)d_in[14];
    float* out = (float*)d_out;

    const int IN_DIM = 512;
    const int N = in_sizes[0] / IN_DIM;   // 50000
    const int E = in_sizes[1];            // 800000

    char* ws = (char*)d_ws;
    size_t off = 0;
    auto alloc = [&](size_t bytes) -> void* {
        void* p = ws + off;
        off = (off + bytes + 255) & ~(size_t)255;
        return p;
    };
    _Float16* featbuf = (_Float16*)alloc((size_t)N * HID * sizeof(_Float16));  // 25.6 MB
    float* el = (float*)alloc((size_t)N * 4 * sizeof(float));
    float* er = (float*)alloc((size_t)N * 4 * sizeof(float));
    int* cnt = (int*)alloc((size_t)N * sizeof(int));
    int* rowptr = (int*)alloc((size_t)(N + 1) * sizeof(int));
    int* cursor = (int*)alloc((size_t)N * sizeof(int));
    int* adj = (int*)alloc((size_t)E * sizeof(int));
    int nscanb = (N + 255) / 256;
    int* bsum = (int*)alloc((size_t)nscanb * sizeof(int));
    int* boff = (int*)alloc((size_t)nscanb * sizeof(int));
    __bf16* Ah = (__bf16*)alloc((size_t)N * HID * sizeof(__bf16));             // 25.6 MB
    __bf16* Al = (__bf16*)alloc((size_t)N * HID * sizeof(__bf16));             // 25.6 MB
    __bf16* Bht0 = (__bf16*)alloc((size_t)512 * HID * sizeof(__bf16));
    __bf16* Blt0 = (__bf16*)alloc((size_t)512 * HID * sizeof(__bf16));
    __bf16* Bht1 = (__bf16*)alloc((size_t)256 * HID * sizeof(__bf16));
    __bf16* Blt1 = (__bf16*)alloc((size_t)256 * HID * sizeof(__bf16));
    __bf16* Bht2 = (__bf16*)alloc((size_t)256 * HID * sizeof(__bf16));
    __bf16* Blt2 = (__bf16*)alloc((size_t)256 * HID * sizeof(__bf16));
    bool use_mfma = (off <= ws_size);

    // CSR build
    hipMemsetAsync(cnt, 0, (size_t)N * sizeof(int), stream);
    hist_kernel<<<(E + 255) / 256, 256, 0, stream>>>(dst, cnt, E);
    scan1_kernel<<<nscanb, 256, 0, stream>>>(cnt, bsum, N);
    scan2_kernel<<<1, 256, 0, stream>>>(bsum, boff, nscanb);
    scan3_kernel<<<nscanb, 256, 0, stream>>>(cnt, boff, rowptr, cursor, N);
    fill_kernel<<<(E + 255) / 256, 256, 0, stream>>>(src, dst, cursor, adj, E);

    dim3 ggrid(HID / 128, (N + 127) / 128);
    int aggb = (N + 3) / 4;

    if (use_mfma) {
        // all weights -> transposed bf16 hi/lo, one kernel
        splitT_all_kernel<<<(512 * 256 + 2 * 256 * 256) / 256, 256, 0, stream>>>(
            W0, W1, W2, Bht0, Blt0, Bht1, Blt1, Bht2, Blt2);

        // layer 0: 512 -> 4x64, relu (A split fused into staging; elr fused)
        gemm_mfma_kernel<true><<<ggrid, 256, 0, stream>>>(
            feats, nullptr, nullptr, Bht0, Blt0, featbuf, al0, ar0, el, er, N, 512, 4);
        agg_tpl<4, true, false, true><<<aggb, 256, 0, stream>>>(
            featbuf, el, er, rowptr, adj, b0, nullptr, Ah, Al, N);

        // layer 1: 256 -> 4x64, relu
        gemm_mfma_kernel<false><<<ggrid, 256, 0, stream>>>(
            nullptr, Ah, Al, Bht1, Blt1, featbuf, al1, ar1, el, er, N, 256, 4);
        agg_tpl<4, true, false, true><<<aggb, 256, 0, stream>>>(
            featbuf, el, er, rowptr, adj, b1, nullptr, Ah, Al, N);

        // layer 2: 256 -> 1x256, no act (elr via atomics -> zero first)
        hipMemsetAsync(el, 0, (size_t)N * 8 * sizeof(float), stream);  // el+er contiguous
        gemm_mfma_kernel<false><<<ggrid, 256, 0, stream>>>(
            nullptr, Ah, Al, Bht2, Blt2, featbuf, al2, ar2, el, er, N, 256, 1);
        agg_tpl<1, false, true, false><<<aggb, 256, 0, stream>>>(
            featbuf, el, er, rowptr, adj, b2, out, nullptr, nullptr, N);
    } else {
        gemm_kernel<<<ggrid, 256, 0, stream>>>(feats, W0, featbuf, N, 512, HID);
        elr_kernel<<<N, 256, 0, stream>>>(featbuf, al0, ar0, el, er, 4);
        agg_tpl<4, true, true, false><<<aggb, 256, 0, stream>>>(
            featbuf, el, er, rowptr, adj, b0, out, nullptr, nullptr, N);

        gemm_kernel<<<ggrid, 256, 0, stream>>>(out, W1, featbuf, N, 256, HID);
        elr_kernel<<<N, 256, 0, stream>>>(featbuf, al1, ar1, el, er, 4);
        agg_tpl<4, true, true, false><<<aggb, 256, 0, stream>>>(
            featbuf, el, er, rowptr, adj, b1, out, nullptr, nullptr, N);

        gemm_kernel<<<ggrid, 256, 0, stream>>>(out, W2, featbuf, N, 256, HID);
        elr_kernel<<<N, 256, 0, stream>>>(featbuf, al2, ar2, el, er, 1);
        agg_tpl<1, false, true, false><<<aggb, 256, 0, stream>>>(
            featbuf, el, er, rowptr, adj, b2, out, nullptr, nullptr, N);
    }
}

// Round 8
// 587.335 us; speedup vs baseline: 1.0461x; 1.0461x over previous
//
#include <hip/hip_runtime.h>
#include <hip/hip_bf16.h>
#include <math.h>

// ---------------------------------------------------------------------------
// GAT 3-layer forward.
//  - L0/L1 GEMMs: A fp16-single x B fp16-split (Bh+Bl), 2 MFMAs per frag pair
//    (error: B ~2^-22, A ~2^-11 -- comparable to the existing fp16 feat path).
//    Single-buffered swizzled LDS (R4 proven schedule), BM=128, 24KB LDS.
//  - L2 GEMM: bf16x3 split (accuracy hedge; feeds output), R6 BM=64 kernel.
//  - agg: wave-per-node, single pass, deferred softmax norm; epilogue writes
//    fp16 A-table (after L0), bf16 hi/lo pair (after L1), fp32 out (after L2).
// ---------------------------------------------------------------------------

#define HID 256

typedef __attribute__((ext_vector_type(8))) __bf16 bf16x8;
typedef __attribute__((ext_vector_type(8))) _Float16 half8;
typedef __attribute__((ext_vector_type(4))) _Float16 half4;
typedef __attribute__((ext_vector_type(4))) float floatx4;

__device__ __forceinline__ void gl_lds16(const void* g, void* l) {
    __builtin_amdgcn_global_load_lds(
        (const __attribute__((address_space(1))) void*)g,
        (__attribute__((address_space(3))) void*)l, 16, 0, 0);
}

// ---------------- CSR build ----------------

__global__ void hist_kernel(const int* __restrict__ dst, int* __restrict__ cnt, int E) {
    int e = blockIdx.x * blockDim.x + threadIdx.x;
    if (e < E) atomicAdd(&cnt[dst[e]], 1);
}

__global__ __launch_bounds__(256) void scan1_kernel(const int* __restrict__ cnt,
                                                    int* __restrict__ bsum, int n) {
    __shared__ int w[4];
    int t = threadIdx.x;
    int i = blockIdx.x * 256 + t;
    int c = (i < n) ? cnt[i] : 0;
    int acc = c;
#pragma unroll
    for (int off = 32; off > 0; off >>= 1) acc += __shfl_xor(acc, off);
    if ((t & 63) == 0) w[t >> 6] = acc;
    __syncthreads();
    if (t == 0) bsum[blockIdx.x] = w[0] + w[1] + w[2] + w[3];
}

__global__ __launch_bounds__(256) void scan2_kernel(const int* __restrict__ bsum,
                                                    int* __restrict__ boff, int nb) {
    __shared__ int buf[256];
    int t = threadIdx.x;
    int v = (t < nb) ? bsum[t] : 0;
    buf[t] = v;
    __syncthreads();
    for (int off = 1; off < 256; off <<= 1) {
        int x = (t >= off) ? buf[t - off] : 0;
        __syncthreads();
        buf[t] += x;
        __syncthreads();
    }
    if (t < nb) boff[t] = buf[t] - v;
}

__global__ __launch_bounds__(256) void scan3_kernel(const int* __restrict__ cnt,
                                                    const int* __restrict__ boff,
                                                    int* __restrict__ rowptr,
                                                    int* __restrict__ cursor, int n) {
    __shared__ int buf[256];
    int t = threadIdx.x;
    int i = blockIdx.x * 256 + t;
    int c = (i < n) ? cnt[i] : 0;
    buf[t] = c;
    __syncthreads();
    for (int off = 1; off < 256; off <<= 1) {
        int x = (t >= off) ? buf[t - off] : 0;
        __syncthreads();
        buf[t] += x;
        __syncthreads();
    }
    int start = boff[blockIdx.x] + buf[t] - c;
    if (i < n) {
        rowptr[i] = start;
        cursor[i] = start;
        if (i == n - 1) rowptr[n] = start + c;
    }
}

__global__ void fill_kernel(const int* __restrict__ src, const int* __restrict__ dst,
                            int* __restrict__ cursor, int* __restrict__ adj, int E) {
    int e = blockIdx.x * blockDim.x + threadIdx.x;
    if (e < E) {
        int d = dst[e];
        int pos = atomicAdd(&cursor[d], 1);
        adj[pos] = src[e];
    }
}

// ------- weights: W0/W1 -> transposed fp16 hi/lo; W2 -> transposed bf16 hi/lo

__device__ __forceinline__ void splitT_f16(const float* W, _Float16* ht, _Float16* lt,
                                           int idx, int K) {
    int k = idx >> 8, n = idx & 255;
    float v = W[idx];
    _Float16 h = (_Float16)v;
    ht[(size_t)n * K + k] = h;
    lt[(size_t)n * K + k] = (_Float16)(v - (float)h);
}

__device__ __forceinline__ void splitT_bf(const float* W, __bf16* ht, __bf16* lt,
                                          int idx, int K) {
    int k = idx >> 8, n = idx & 255;
    float v = W[idx];
    __bf16 h = (__bf16)v;
    ht[(size_t)n * K + k] = h;
    lt[(size_t)n * K + k] = (__bf16)(v - (float)h);
}

__global__ __launch_bounds__(256) void splitT_all_kernel(
    const float* __restrict__ W0, const float* __restrict__ W1,
    const float* __restrict__ W2, _Float16* h0, _Float16* l0, _Float16* h1,
    _Float16* l1, __bf16* h2, __bf16* l2) {
    int i = blockIdx.x * 256 + threadIdx.x;
    const int n0 = 512 * 256, n1 = 256 * 256;
    if (i < n0) splitT_f16(W0, h0, l0, i, 512);
    else if (i < n0 + n1) splitT_f16(W1, h1, l1, i - n0, 256);
    else if (i < n0 + 2 * n1) splitT_bf(W2, h2, l2, i - n0 - n1, 256);
}

// ---------------- fp16 MFMA GEMM (L0/L1) + fused elr ----------------
// C[M,256](fp16) = A(fp16) @ (Bh+Bl)(fp16);  2 MFMAs per fragment pair.
// BM=128, BN=128, BK=32; single-buffer swizzled LDS (R4 schedule); 24KB.
// SPLITA: A is fp32 (feats), cvt to fp16 in registers during staging.

template <bool SPLITA>
__global__ __launch_bounds__(256, 2) void gemm_f16_kernel(
    const float* __restrict__ Af, const _Float16* __restrict__ A16,
    const _Float16* __restrict__ Bht, const _Float16* __restrict__ Blt,
    _Float16* __restrict__ C, const float* __restrict__ al,
    const float* __restrict__ ar, float* __restrict__ el,
    float* __restrict__ er, int M, int K, int H) {
    __shared__ _Float16 sA[128 * 32];   // 8 KB
    __shared__ _Float16 sBh[128 * 32];  // 8 KB
    __shared__ _Float16 sBl[128 * 32];  // 8 KB

    int t = threadIdx.x;
    int wave = t >> 6, lane = t & 63;
    int wr = wave >> 1, wc = wave & 1;
    int quad = lane >> 4, m16 = lane & 15;

    int rowA0 = blockIdx.y * 128;
    int rowB0 = blockIdx.x * 128;

    // gl_lds staging: thread t -> LDS chunk t*16B = (row t>>2, slot t&3);
    // global slot swizzled (t&3)^((t>>3)&3).
    int sr = t >> 2;
    int ke = ((t & 3) ^ ((t >> 3) & 3)) * 8;
    int ldso = t * 8;
    // SPLITA: thread t -> row t>>1, cols (t&1)*16..+16, swizzled slots
    int srow = t >> 1;
    int kb = (t & 1) * 16;
    int s0 = (t & 1) * 2;
    int ssw = (srow >> 1) & 3;
    int soA = srow * 32 + (s0 ^ ssw) * 8;
    int soB = srow * 32 + ((s0 + 1) ^ ssw) * 8;

    size_t ar0 = 0, ar1 = 0, af0 = 0;
    if (SPLITA) {
        af0 = (size_t)min(rowA0 + srow, M - 1) * K + kb;
    } else {
        ar0 = (size_t)min(rowA0 + sr, M - 1) * K;
        ar1 = (size_t)min(rowA0 + sr + 64, M - 1) * K;
    }
    size_t br0 = (size_t)(rowB0 + sr) * K;
    size_t br1 = (size_t)(rowB0 + sr + 64) * K;

    int qsw = (quad ^ ((m16 >> 1) & 3)) * 8;

    floatx4 acc[4][4];
    floatx4 z = {0.f, 0.f, 0.f, 0.f};
#pragma unroll
    for (int i = 0; i < 4; i++)
#pragma unroll
        for (int j = 0; j < 4; j++) acc[i][j] = z;

    int nk = K >> 5;
    for (int kt = 0; kt < nk; kt++) {
        int k0 = kt << 5;
        int k0s = k0 + ke;
        gl_lds16(Bht + br0 + k0s, &sBh[ldso]);
        gl_lds16(Bht + br1 + k0s, &sBh[2048 + ldso]);
        gl_lds16(Blt + br0 + k0s, &sBl[ldso]);
        gl_lds16(Blt + br1 + k0s, &sBl[2048 + ldso]);
        if (SPLITA) {
            const float* ap = Af + af0 + k0;
            float4 v0 = ((const float4*)ap)[0];
            float4 v1 = ((const float4*)ap)[1];
            float4 v2 = ((const float4*)ap)[2];
            float4 v3 = ((const float4*)ap)[3];
            float vv[16] = {v0.x, v0.y, v0.z, v0.w, v1.x, v1.y, v1.z, v1.w,
                            v2.x, v2.y, v2.z, v2.w, v3.x, v3.y, v3.z, v3.w};
            half8 h0, h1;
#pragma unroll
            for (int c = 0; c < 8; c++) {
                h0[c] = (_Float16)vv[c];
                h1[c] = (_Float16)vv[8 + c];
            }
            *(half8*)&sA[soA] = h0;
            *(half8*)&sA[soB] = h1;
        } else {
            gl_lds16(A16 + ar0 + k0s, &sA[ldso]);
            gl_lds16(A16 + ar1 + k0s, &sA[2048 + ldso]);
        }
        __syncthreads();

        half8 fa[4], fbh[4], fbl[4];
#pragma unroll
        for (int i = 0; i < 4; i++) {
            int off = (wr * 64 + i * 16 + m16) * 32 + qsw;
            fa[i] = *(const half8*)&sA[off];
        }
#pragma unroll
        for (int j = 0; j < 4; j++) {
            int off = (wc * 64 + j * 16 + m16) * 32 + qsw;
            fbh[j] = *(const half8*)&sBh[off];
            fbl[j] = *(const half8*)&sBl[off];
        }
#pragma unroll
        for (int i = 0; i < 4; i++)
#pragma unroll
            for (int j = 0; j < 4; j++) {
                acc[i][j] = __builtin_amdgcn_mfma_f32_16x16x32_f16(fa[i], fbh[j], acc[i][j], 0, 0, 0);
                acc[i][j] = __builtin_amdgcn_mfma_f32_16x16x32_f16(fa[i], fbl[j], acc[i][j], 0, 0, 0);
            }
        __syncthreads();
    }

    // C store (C/D layout: col = m16, row = quad*4 + reg)
#pragma unroll
    for (int i = 0; i < 4; i++) {
        int rowb = rowA0 + wr * 64 + i * 16 + quad * 4;
#pragma unroll
        for (int j = 0; j < 4; j++) {
            int col = rowB0 + wc * 64 + j * 16 + m16;
#pragma unroll
            for (int r = 0; r < 4; r++) {
                int row = rowb + r;
                if (row < M) C[(size_t)row * HID + col] = (_Float16)acc[i][j][r];
            }
        }
    }

    // fused elr
    float alv[4], arv[4];
#pragma unroll
    for (int j = 0; j < 4; j++) {
        int col = rowB0 + wc * 64 + j * 16 + m16;
        alv[j] = al[col];
        arv[j] = ar[col];
    }
    int h = ((rowB0 + wc * 64) >> 6) & (H - 1);
#pragma unroll
    for (int i = 0; i < 4; i++) {
        int rowb = rowA0 + wr * 64 + i * 16 + quad * 4;
#pragma unroll
        for (int r = 0; r < 4; r++) {
            float pe = acc[i][0][r] * alv[0] + acc[i][1][r] * alv[1] +
                       acc[i][2][r] * alv[2] + acc[i][3][r] * alv[3];
            float pr = acc[i][0][r] * arv[0] + acc[i][1][r] * arv[1] +
                       acc[i][2][r] * arv[2] + acc[i][3][r] * arv[3];
#pragma unroll
            for (int off = 1; off < 16; off <<= 1) {
                pe += __shfl_xor(pe, off);
                pr += __shfl_xor(pr, off);
            }
            int row = rowb + r;
            if (m16 == 0 && row < M) {
                el[row * 4 + h] = pe;
                er[row * 4 + h] = pr;
            }
        }
    }
}

// ---------------- bf16x3 MFMA GEMM (L2, accuracy hedge; R6 BM=64) ----------

__global__ __launch_bounds__(256, 4) void gemm_bf3_kernel(
    const __bf16* __restrict__ Ah, const __bf16* __restrict__ Al,
    const __bf16* __restrict__ Bht, const __bf16* __restrict__ Blt,
    _Float16* __restrict__ C, const float* __restrict__ al,
    const float* __restrict__ ar, float* __restrict__ el,
    float* __restrict__ er, int M, int K, int H) {
    __shared__ __bf16 sAh[64 * 32];
    __shared__ __bf16 sAl[64 * 32];
    __shared__ __bf16 sBh[128 * 32];
    __shared__ __bf16 sBl[128 * 32];

    int t = threadIdx.x;
    int wave = t >> 6, lane = t & 63;
    int wr = wave >> 1, wc = wave & 1;
    int quad = lane >> 4, m16 = lane & 15;

    int rowA0 = blockIdx.y * 64;
    int rowB0 = blockIdx.x * 128;

    int sr = t >> 2;
    int ke = ((t & 3) ^ ((t >> 3) & 3)) * 8;
    int ldso = t * 8;

    size_t ar0 = (size_t)min(rowA0 + sr, M - 1) * K;
    size_t br0 = (size_t)(rowB0 + sr) * K;
    size_t br1 = (size_t)(rowB0 + sr + 64) * K;

    int qsw = (quad ^ ((m16 >> 1) & 3)) * 8;

    floatx4 acc[2][4];
    floatx4 z = {0.f, 0.f, 0.f, 0.f};
#pragma unroll
    for (int i = 0; i < 2; i++)
#pragma unroll
        for (int j = 0; j < 4; j++) acc[i][j] = z;

    int nk = K >> 5;
    for (int kt = 0; kt < nk; kt++) {
        int k0s = (kt << 5) + ke;
        gl_lds16(Bht + br0 + k0s, &sBh[ldso]);
        gl_lds16(Bht + br1 + k0s, &sBh[2048 + ldso]);
        gl_lds16(Blt + br0 + k0s, &sBl[ldso]);
        gl_lds16(Blt + br1 + k0s, &sBl[2048 + ldso]);
        gl_lds16(Ah + ar0 + k0s, &sAh[ldso]);
        gl_lds16(Al + ar0 + k0s, &sAl[ldso]);
        __syncthreads();

        bf16x8 fah[2], fal[2], fbh[4], fbl[4];
#pragma unroll
        for (int i = 0; i < 2; i++) {
            int off = (wr * 32 + i * 16 + m16) * 32 + qsw;
            fah[i] = *(const bf16x8*)&sAh[off];
            fal[i] = *(const bf16x8*)&sAl[off];
        }
#pragma unroll
        for (int j = 0; j < 4; j++) {
            int off = (wc * 64 + j * 16 + m16) * 32 + qsw;
            fbh[j] = *(const bf16x8*)&sBh[off];
            fbl[j] = *(const bf16x8*)&sBl[off];
        }
#pragma unroll
        for (int i = 0; i < 2; i++)
#pragma unroll
            for (int j = 0; j < 4; j++) {
                acc[i][j] = __builtin_amdgcn_mfma_f32_16x16x32_bf16(fah[i], fbh[j], acc[i][j], 0, 0, 0);
                acc[i][j] = __builtin_amdgcn_mfma_f32_16x16x32_bf16(fah[i], fbl[j], acc[i][j], 0, 0, 0);
                acc[i][j] = __builtin_amdgcn_mfma_f32_16x16x32_bf16(fal[i], fbh[j], acc[i][j], 0, 0, 0);
            }
        __syncthreads();
    }

#pragma unroll
    for (int i = 0; i < 2; i++) {
        int rowb = rowA0 + wr * 32 + i * 16 + quad * 4;
#pragma unroll
        for (int j = 0; j < 4; j++) {
            int col = rowB0 + wc * 64 + j * 16 + m16;
#pragma unroll
            for (int r = 0; r < 4; r++) {
                int row = rowb + r;
                if (row < M) C[(size_t)row * HID + col] = (_Float16)acc[i][j][r];
            }
        }
    }

    // fused elr (H==1: atomic accumulate across the two wc column-halves)
    float alv[4], arv[4];
#pragma unroll
    for (int j = 0; j < 4; j++) {
        int col = rowB0 + wc * 64 + j * 16 + m16;
        alv[j] = al[col];
        arv[j] = ar[col];
    }
    int h = ((rowB0 + wc * 64) >> 6) & (H - 1);
#pragma unroll
    for (int i = 0; i < 2; i++) {
        int rowb = rowA0 + wr * 32 + i * 16 + quad * 4;
#pragma unroll
        for (int r = 0; r < 4; r++) {
            float pe = acc[i][0][r] * alv[0] + acc[i][1][r] * alv[1] +
                       acc[i][2][r] * alv[2] + acc[i][3][r] * alv[3];
            float pr = acc[i][0][r] * arv[0] + acc[i][1][r] * arv[1] +
                       acc[i][2][r] * arv[2] + acc[i][3][r] * arv[3];
#pragma unroll
            for (int off = 1; off < 16; off <<= 1) {
                pe += __shfl_xor(pe, off);
                pr += __shfl_xor(pr, off);
            }
            int row = rowb + r;
            if (m16 == 0 && row < M) {
                if (H == 4) {
                    el[row * 4 + h] = pe;
                    er[row * 4 + h] = pr;
                } else {
                    atomicAdd(&el[row], pe);
                    atomicAdd(&er[row], pr);
                }
            }
        }
    }
}

// ---------------- agg: wave-per-node, single pass, deferred softmax norm ----
// WMODE: 0 = fp32 out, 1 = bf16 hi/lo pair, 2 = fp16 single table.

template <int H, bool RELU, int WMODE>
__global__ __launch_bounds__(256) void agg_tpl(
    const _Float16* __restrict__ feat, const float* __restrict__ el,
    const float* __restrict__ er, const int* __restrict__ rowptr,
    const int* __restrict__ adj, const float* __restrict__ bias,
    float* __restrict__ outf, __bf16* __restrict__ oh, __bf16* __restrict__ ol,
    _Float16* __restrict__ oa, int N) {
    int wave = threadIdx.x >> 6, lane = threadIdx.x & 63;
    int v = blockIdx.x * 4 + wave;
    if (v >= N) return;
    int row0 = rowptr[v];
    int deg = rowptr[v + 1] - row0;

    int l32 = lane & 31;
    int half = lane >> 5;
    int hd = (H == 4) ? (l32 >> 3) : 0;
    int d0 = l32 * 8;

    float o[8];
    if (deg > 0) {
        float er_h = (H == 4) ? er[v * 4 + hd] : er[v];
        const int* adjr = adj + row0;

        float a[8];
#pragma unroll
        for (int j = 0; j < 8; j++) a[j] = 0.f;
        float sl = 0.f;

        int e = 0;
        for (; e + 16 <= deg; e += 16) {
            int u[8];
            half8 f[8];
            float elv[8];
#pragma unroll
            for (int q = 0; q < 8; q++) u[q] = adjr[e + q * 2 + half];
#pragma unroll
            for (int q = 0; q < 8; q++)
                f[q] = *(const half8*)&feat[(size_t)u[q] * HID + d0];
#pragma unroll
            for (int q = 0; q < 8; q++)
                elv[q] = (H == 4) ? el[u[q] * 4 + hd] : el[u[q]];
#pragma unroll
            for (int q = 0; q < 8; q++) {
                float sc = elv[q] + er_h;
                sc = (sc > 0.f) ? sc : 0.2f * sc;
                float ex = __expf(sc);
                sl += ex;
#pragma unroll
                for (int j = 0; j < 8; j++) a[j] = fmaf(ex, (float)f[q][j], a[j]);
            }
        }
        for (; e + 8 <= deg; e += 8) {
            int u[4];
            half8 f[4];
            float elv[4];
#pragma unroll
            for (int q = 0; q < 4; q++) u[q] = adjr[e + q * 2 + half];
#pragma unroll
            for (int q = 0; q < 4; q++)
                f[q] = *(const half8*)&feat[(size_t)u[q] * HID + d0];
#pragma unroll
            for (int q = 0; q < 4; q++)
                elv[q] = (H == 4) ? el[u[q] * 4 + hd] : el[u[q]];
#pragma unroll
            for (int q = 0; q < 4; q++) {
                float sc = elv[q] + er_h;
                sc = (sc > 0.f) ? sc : 0.2f * sc;
                float ex = __expf(sc);
                sl += ex;
#pragma unroll
                for (int j = 0; j < 8; j++) a[j] = fmaf(ex, (float)f[q][j], a[j]);
            }
        }
        for (; e < deg; e += 2) {
            int ee = e + half;
            bool act = ee < deg;
            int es = act ? ee : (deg - 1);
            int u = adjr[es];
            float elvq = (H == 4) ? el[u * 4 + hd] : el[u];
            half8 f = *(const half8*)&feat[(size_t)u * HID + d0];
            float sc = elvq + er_h;
            sc = (sc > 0.f) ? sc : 0.2f * sc;
            float ex = act ? __expf(sc) : 0.f;
            sl += ex;
#pragma unroll
            for (int j = 0; j < 8; j++) a[j] = fmaf(ex, (float)f[j], a[j]);
        }

#pragma unroll
        for (int j = 0; j < 8; j++) a[j] += __shfl_xor(a[j], 32);
        sl += __shfl_xor(sl, 32);
        float inv = 1.f / sl;

#pragma unroll
        for (int j = 0; j < 8; j++) {
            o[j] = fmaf(a[j], inv, bias[d0 + j]);
            if (RELU) o[j] = fmaxf(o[j], 0.f);
        }
    } else {
#pragma unroll
        for (int j = 0; j < 8; j++) {
            o[j] = bias[d0 + j];
            if (RELU) o[j] = fmaxf(o[j], 0.f);
        }
    }

    if (half == 0) {
        size_t base = (size_t)v * HID + d0;
        if (WMODE == 0) {
            *(float4*)&outf[base] = make_float4(o[0], o[1], o[2], o[3]);
            *(float4*)&outf[base + 4] = make_float4(o[4], o[5], o[6], o[7]);
        } else if (WMODE == 1) {
            bf16x8 hh, ll;
#pragma unroll
            for (int j = 0; j < 8; j++) {
                __bf16 hv = (__bf16)o[j];
                hh[j] = hv;
                ll[j] = (__bf16)(o[j] - (float)hv);
            }
            *(bf16x8*)&oh[base] = hh;
            *(bf16x8*)&ol[base] = ll;
        } else {
            half8 ha;
#pragma unroll
            for (int j = 0; j < 8; j++) ha[j] = (_Float16)o[j];
            *(half8*)&oa[base] = ha;
        }
    }
}

// ---------------- launch ----------------

extern "C" void kernel_launch(void* const* d_in, const int* in_sizes, int n_in,
                              void* d_out, int out_size, void* d_ws, size_t ws_size,
                              hipStream_t stream) {
    const float* feats = (const float*)d_in[0];
    const int* src = (const int*)d_in[1];
    const int* dst = (const int*)d_in[2];
    const float* W0 = (const float*)d_in[3];
    const float* al0 = (const float*)d_in[4];
    const float* ar0 = (const float*)d_in[5];
    const float* b0 = (const float*)d_in[6];
    const float* W1 = (const float*)d_in[7];
    const float* al1 = (const float*)d_in[8];
    const float* ar1 = (const float*)d_in[9];
    const float* b1 = (const float*)d_in[10];
    const float* W2 = (const float*)d_in[11];
    const float* al2 = (const float*)d_in[12];
    const float* ar2 = (const float*)d_in[13];
    const float* b2 = (const float*)d_in[14];
    float* out = (float*)d_out;

    const int IN_DIM = 512;
    const int N = in_sizes[0] / IN_DIM;   // 50000
    const int E = in_sizes[1];            // 800000

    char* ws = (char*)d_ws;
    size_t off = 0;
    auto alloc = [&](size_t bytes) -> void* {
        void* p = ws + off;
        off = (off + bytes + 255) & ~(size_t)255;
        return p;
    };
    _Float16* featbuf = (_Float16*)alloc((size_t)N * HID * sizeof(_Float16));  // 25.6 MB
    _Float16* featA = (_Float16*)alloc((size_t)N * HID * sizeof(_Float16));    // 25.6 MB
    float* el = (float*)alloc((size_t)N * 4 * sizeof(float));
    float* er = (float*)alloc((size_t)N * 4 * sizeof(float));
    int* cnt = (int*)alloc((size_t)N * sizeof(int));
    int* rowptr = (int*)alloc((size_t)(N + 1) * sizeof(int));
    int* cursor = (int*)alloc((size_t)N * sizeof(int));
    int* adj = (int*)alloc((size_t)E * sizeof(int));
    int nscanb = (N + 255) / 256;
    int* bsum = (int*)alloc((size_t)nscanb * sizeof(int));
    int* boff = (int*)alloc((size_t)nscanb * sizeof(int));
    __bf16* Ah = (__bf16*)alloc((size_t)N * HID * sizeof(__bf16));             // 25.6 MB
    __bf16* Al = (__bf16*)alloc((size_t)N * HID * sizeof(__bf16));             // 25.6 MB
    _Float16* Bht0 = (_Float16*)alloc((size_t)512 * HID * sizeof(_Float16));
    _Float16* Blt0 = (_Float16*)alloc((size_t)512 * HID * sizeof(_Float16));
    _Float16* Bht1 = (_Float16*)alloc((size_t)256 * HID * sizeof(_Float16));
    _Float16* Blt1 = (_Float16*)alloc((size_t)256 * HID * sizeof(_Float16));
    __bf16* Bht2 = (__bf16*)alloc((size_t)256 * HID * sizeof(__bf16));
    __bf16* Blt2 = (__bf16*)alloc((size_t)256 * HID * sizeof(__bf16));
    (void)ws_size;

    // CSR build
    hipMemsetAsync(cnt, 0, (size_t)N * sizeof(int), stream);
    hist_kernel<<<(E + 255) / 256, 256, 0, stream>>>(dst, cnt, E);
    scan1_kernel<<<nscanb, 256, 0, stream>>>(cnt, bsum, N);
    scan2_kernel<<<1, 256, 0, stream>>>(bsum, boff, nscanb);
    scan3_kernel<<<nscanb, 256, 0, stream>>>(cnt, boff, rowptr, cursor, N);
    fill_kernel<<<(E + 255) / 256, 256, 0, stream>>>(src, dst, cursor, adj, E);

    dim3 ggrid128(HID / 128, (N + 127) / 128);
    dim3 ggrid64(HID / 128, (N + 63) / 64);
    int aggb = (N + 3) / 4;

    // weights
    splitT_all_kernel<<<(512 * 256 + 2 * 256 * 256) / 256, 256, 0, stream>>>(
        W0, W1, W2, Bht0, Blt0, Bht1, Blt1, Bht2, Blt2);

    // layer 0: fp16 GEMM (A split from fp32 in-kernel), agg -> fp16 A-table
    gemm_f16_kernel<true><<<ggrid128, 256, 0, stream>>>(
        feats, nullptr, Bht0, Blt0, featbuf, al0, ar0, el, er, N, 512, 4);
    agg_tpl<4, true, 2><<<aggb, 256, 0, stream>>>(
        featbuf, el, er, rowptr, adj, b0, nullptr, nullptr, nullptr, featA, N);

    // layer 1: fp16 GEMM, agg -> bf16 hi/lo pair (for L2's bf16x3)
    gemm_f16_kernel<false><<<ggrid128, 256, 0, stream>>>(
        nullptr, featA, Bht1, Blt1, featbuf, al1, ar1, el, er, N, 256, 4);
    agg_tpl<4, true, 1><<<aggb, 256, 0, stream>>>(
        featbuf, el, er, rowptr, adj, b1, nullptr, Ah, Al, nullptr, N);

    // layer 2: bf16x3 GEMM (accuracy hedge), elr via atomics -> zero first
    hipMemsetAsync(el, 0, (size_t)N * 8 * sizeof(float), stream);  // el+er contiguous
    gemm_bf3_kernel<<<ggrid64, 256, 0, stream>>>(
        Ah, Al, Bht2, Blt2, featbuf, al2, ar2, el, er, N, 256, 1);
    agg_tpl<1, false, 0><<<aggb, 256, 0, stream>>>(
        featbuf, el, er, rowptr, adj, b2, out, nullptr, nullptr, nullptr, N);
}

// Round 9
// 578.642 us; speedup vs baseline: 1.0618x; 1.0150x over previous
//
#include <hip/hip_runtime.h>
#include <hip/hip_bf16.h>
#include <math.h>

// ---------------------------------------------------------------------------
// GAT 3-layer forward.
//  - ALL GEMMs: A fp16-single x B fp16-split (Bh+Bl), 2 MFMAs per frag pair
//    (B reconstructs to ~2^-22; A adds ~2^-11 -- measured free at L0/L1 in R8,
//    now extended to L2). Single-buffered swizzled LDS (R4 proven schedule),
//    BM=128, 24KB LDS, elr fused in epilogue (H=1 via atomics for L2).
//  - agg: wave-per-node, single pass, deferred softmax norm; epilogue writes
//    one fp16 feat table between layers (no more bf16 hi/lo pair).
// ---------------------------------------------------------------------------

#define HID 256

typedef __attribute__((ext_vector_type(8))) _Float16 half8;
typedef __attribute__((ext_vector_type(4))) _Float16 half4;
typedef __attribute__((ext_vector_type(4))) float floatx4;

__device__ __forceinline__ void gl_lds16(const void* g, void* l) {
    __builtin_amdgcn_global_load_lds(
        (const __attribute__((address_space(1))) void*)g,
        (__attribute__((address_space(3))) void*)l, 16, 0, 0);
}

// ---------------- CSR build ----------------

__global__ void hist_kernel(const int* __restrict__ dst, int* __restrict__ cnt, int E) {
    int e = blockIdx.x * blockDim.x + threadIdx.x;
    if (e < E) atomicAdd(&cnt[dst[e]], 1);
}

__global__ __launch_bounds__(256) void scan1_kernel(const int* __restrict__ cnt,
                                                    int* __restrict__ bsum, int n) {
    __shared__ int w[4];
    int t = threadIdx.x;
    int i = blockIdx.x * 256 + t;
    int c = (i < n) ? cnt[i] : 0;
    int acc = c;
#pragma unroll
    for (int off = 32; off > 0; off >>= 1) acc += __shfl_xor(acc, off);
    if ((t & 63) == 0) w[t >> 6] = acc;
    __syncthreads();
    if (t == 0) bsum[blockIdx.x] = w[0] + w[1] + w[2] + w[3];
}

__global__ __launch_bounds__(256) void scan2_kernel(const int* __restrict__ bsum,
                                                    int* __restrict__ boff, int nb) {
    __shared__ int buf[256];
    int t = threadIdx.x;
    int v = (t < nb) ? bsum[t] : 0;
    buf[t] = v;
    __syncthreads();
    for (int off = 1; off < 256; off <<= 1) {
        int x = (t >= off) ? buf[t - off] : 0;
        __syncthreads();
        buf[t] += x;
        __syncthreads();
    }
    if (t < nb) boff[t] = buf[t] - v;
}

__global__ __launch_bounds__(256) void scan3_kernel(const int* __restrict__ cnt,
                                                    const int* __restrict__ boff,
                                                    int* __restrict__ rowptr,
                                                    int* __restrict__ cursor, int n) {
    __shared__ int buf[256];
    int t = threadIdx.x;
    int i = blockIdx.x * 256 + t;
    int c = (i < n) ? cnt[i] : 0;
    buf[t] = c;
    __syncthreads();
    for (int off = 1; off < 256; off <<= 1) {
        int x = (t >= off) ? buf[t - off] : 0;
        __syncthreads();
        buf[t] += x;
        __syncthreads();
    }
    int start = boff[blockIdx.x] + buf[t] - c;
    if (i < n) {
        rowptr[i] = start;
        cursor[i] = start;
        if (i == n - 1) rowptr[n] = start + c;
    }
}

__global__ void fill_kernel(const int* __restrict__ src, const int* __restrict__ dst,
                            int* __restrict__ cursor, int* __restrict__ adj, int E) {
    int e = blockIdx.x * blockDim.x + threadIdx.x;
    if (e < E) {
        int d = dst[e];
        int pos = atomicAdd(&cursor[d], 1);
        adj[pos] = src[e];
    }
}

// ---------- weights: all -> transposed fp16 hi/lo ----------

__device__ __forceinline__ void splitT_f16(const float* W, _Float16* ht, _Float16* lt,
                                           int idx, int K) {
    int k = idx >> 8, n = idx & 255;
    float v = W[idx];
    _Float16 h = (_Float16)v;
    ht[(size_t)n * K + k] = h;
    lt[(size_t)n * K + k] = (_Float16)(v - (float)h);
}

__global__ __launch_bounds__(256) void splitT_all_kernel(
    const float* __restrict__ W0, const float* __restrict__ W1,
    const float* __restrict__ W2, _Float16* h0, _Float16* l0, _Float16* h1,
    _Float16* l1, _Float16* h2, _Float16* l2) {
    int i = blockIdx.x * 256 + threadIdx.x;
    const int n0 = 512 * 256, n1 = 256 * 256;
    if (i < n0) splitT_f16(W0, h0, l0, i, 512);
    else if (i < n0 + n1) splitT_f16(W1, h1, l1, i - n0, 256);
    else if (i < n0 + 2 * n1) splitT_f16(W2, h2, l2, i - n0 - n1, 256);
}

// ---------------- fp16 MFMA GEMM + fused elr ----------------
// C[M,256](fp16) = A(fp16) @ (Bh+Bl)(fp16);  2 MFMAs per fragment pair.
// BM=128, BN=128, BK=32; single-buffer swizzled LDS (R4 schedule); 24KB.
// SPLITA: A is fp32 (feats), cvt to fp16 in registers during staging.
// H==4: direct elr store; H==1: atomic accumulate (el/er pre-zeroed).

template <bool SPLITA>
__global__ __launch_bounds__(256, 2) void gemm_f16_kernel(
    const float* __restrict__ Af, const _Float16* __restrict__ A16,
    const _Float16* __restrict__ Bht, const _Float16* __restrict__ Blt,
    _Float16* __restrict__ C, const float* __restrict__ al,
    const float* __restrict__ ar, float* __restrict__ el,
    float* __restrict__ er, int M, int K, int H) {
    __shared__ _Float16 sA[128 * 32];   // 8 KB
    __shared__ _Float16 sBh[128 * 32];  // 8 KB
    __shared__ _Float16 sBl[128 * 32];  // 8 KB

    int t = threadIdx.x;
    int wave = t >> 6, lane = t & 63;
    int wr = wave >> 1, wc = wave & 1;
    int quad = lane >> 4, m16 = lane & 15;

    int rowA0 = blockIdx.y * 128;
    int rowB0 = blockIdx.x * 128;

    // gl_lds staging: thread t -> LDS chunk t*16B = (row t>>2, slot t&3);
    // global slot swizzled (t&3)^((t>>3)&3).
    int sr = t >> 2;
    int ke = ((t & 3) ^ ((t >> 3) & 3)) * 8;
    int ldso = t * 8;
    // SPLITA: thread t -> row t>>1, cols (t&1)*16..+16, swizzled slots
    int srow = t >> 1;
    int kb = (t & 1) * 16;
    int s0 = (t & 1) * 2;
    int ssw = (srow >> 1) & 3;
    int soA = srow * 32 + (s0 ^ ssw) * 8;
    int soB = srow * 32 + ((s0 + 1) ^ ssw) * 8;

    size_t ar0 = 0, ar1 = 0, af0 = 0;
    if (SPLITA) {
        af0 = (size_t)min(rowA0 + srow, M - 1) * K + kb;
    } else {
        ar0 = (size_t)min(rowA0 + sr, M - 1) * K;
        ar1 = (size_t)min(rowA0 + sr + 64, M - 1) * K;
    }
    size_t br0 = (size_t)(rowB0 + sr) * K;
    size_t br1 = (size_t)(rowB0 + sr + 64) * K;

    int qsw = (quad ^ ((m16 >> 1) & 3)) * 8;

    floatx4 acc[4][4];
    floatx4 z = {0.f, 0.f, 0.f, 0.f};
#pragma unroll
    for (int i = 0; i < 4; i++)
#pragma unroll
        for (int j = 0; j < 4; j++) acc[i][j] = z;

    int nk = K >> 5;
    for (int kt = 0; kt < nk; kt++) {
        int k0 = kt << 5;
        int k0s = k0 + ke;
        gl_lds16(Bht + br0 + k0s, &sBh[ldso]);
        gl_lds16(Bht + br1 + k0s, &sBh[2048 + ldso]);
        gl_lds16(Blt + br0 + k0s, &sBl[ldso]);
        gl_lds16(Blt + br1 + k0s, &sBl[2048 + ldso]);
        if (SPLITA) {
            const float* ap = Af + af0 + k0;
            float4 v0 = ((const float4*)ap)[0];
            float4 v1 = ((const float4*)ap)[1];
            float4 v2 = ((const float4*)ap)[2];
            float4 v3 = ((const float4*)ap)[3];
            float vv[16] = {v0.x, v0.y, v0.z, v0.w, v1.x, v1.y, v1.z, v1.w,
                            v2.x, v2.y, v2.z, v2.w, v3.x, v3.y, v3.z, v3.w};
            half8 h0, h1;
#pragma unroll
            for (int c = 0; c < 8; c++) {
                h0[c] = (_Float16)vv[c];
                h1[c] = (_Float16)vv[8 + c];
            }
            *(half8*)&sA[soA] = h0;
            *(half8*)&sA[soB] = h1;
        } else {
            gl_lds16(A16 + ar0 + k0s, &sA[ldso]);
            gl_lds16(A16 + ar1 + k0s, &sA[2048 + ldso]);
        }
        __syncthreads();

        half8 fa[4], fbh[4], fbl[4];
#pragma unroll
        for (int i = 0; i < 4; i++) {
            int off = (wr * 64 + i * 16 + m16) * 32 + qsw;
            fa[i] = *(const half8*)&sA[off];
        }
#pragma unroll
        for (int j = 0; j < 4; j++) {
            int off = (wc * 64 + j * 16 + m16) * 32 + qsw;
            fbh[j] = *(const half8*)&sBh[off];
            fbl[j] = *(const half8*)&sBl[off];
        }
#pragma unroll
        for (int i = 0; i < 4; i++)
#pragma unroll
            for (int j = 0; j < 4; j++) {
                acc[i][j] = __builtin_amdgcn_mfma_f32_16x16x32_f16(fa[i], fbh[j], acc[i][j], 0, 0, 0);
                acc[i][j] = __builtin_amdgcn_mfma_f32_16x16x32_f16(fa[i], fbl[j], acc[i][j], 0, 0, 0);
            }
        __syncthreads();
    }

    // C store (C/D layout: col = m16, row = quad*4 + reg)
#pragma unroll
    for (int i = 0; i < 4; i++) {
        int rowb = rowA0 + wr * 64 + i * 16 + quad * 4;
#pragma unroll
        for (int j = 0; j < 4; j++) {
            int col = rowB0 + wc * 64 + j * 16 + m16;
#pragma unroll
            for (int r = 0; r < 4; r++) {
                int row = rowb + r;
                if (row < M) C[(size_t)row * HID + col] = (_Float16)acc[i][j][r];
            }
        }
    }

    // fused elr
    float alv[4], arv[4];
#pragma unroll
    for (int j = 0; j < 4; j++) {
        int col = rowB0 + wc * 64 + j * 16 + m16;
        alv[j] = al[col];
        arv[j] = ar[col];
    }
    int h = ((rowB0 + wc * 64) >> 6) & (H - 1);
#pragma unroll
    for (int i = 0; i < 4; i++) {
        int rowb = rowA0 + wr * 64 + i * 16 + quad * 4;
#pragma unroll
        for (int r = 0; r < 4; r++) {
            float pe = acc[i][0][r] * alv[0] + acc[i][1][r] * alv[1] +
                       acc[i][2][r] * alv[2] + acc[i][3][r] * alv[3];
            float pr = acc[i][0][r] * arv[0] + acc[i][1][r] * arv[1] +
                       acc[i][2][r] * arv[2] + acc[i][3][r] * arv[3];
#pragma unroll
            for (int off = 1; off < 16; off <<= 1) {
                pe += __shfl_xor(pe, off);
                pr += __shfl_xor(pr, off);
            }
            int row = rowb + r;
            if (m16 == 0 && row < M) {
                if (H == 4) {
                    el[row * 4 + h] = pe;
                    er[row * 4 + h] = pr;
                } else {
                    atomicAdd(&el[row], pe);
                    atomicAdd(&er[row], pr);
                }
            }
        }
    }
}

// ---------------- agg: wave-per-node, single pass, deferred softmax norm ----
// WMODE: 0 = fp32 out, 2 = fp16 single table.

template <int H, bool RELU, int WMODE>
__global__ __launch_bounds__(256) void agg_tpl(
    const _Float16* __restrict__ feat, const float* __restrict__ el,
    const float* __restrict__ er, const int* __restrict__ rowptr,
    const int* __restrict__ adj, const float* __restrict__ bias,
    float* __restrict__ outf, _Float16* __restrict__ oa, int N) {
    int wave = threadIdx.x >> 6, lane = threadIdx.x & 63;
    int v = blockIdx.x * 4 + wave;
    if (v >= N) return;
    int row0 = rowptr[v];
    int deg = rowptr[v + 1] - row0;

    int l32 = lane & 31;
    int half = lane >> 5;
    int hd = (H == 4) ? (l32 >> 3) : 0;
    int d0 = l32 * 8;

    float o[8];
    if (deg > 0) {
        float er_h = (H == 4) ? er[v * 4 + hd] : er[v];
        const int* adjr = adj + row0;

        float a[8];
#pragma unroll
        for (int j = 0; j < 8; j++) a[j] = 0.f;
        float sl = 0.f;

        int e = 0;
        for (; e + 16 <= deg; e += 16) {
            int u[8];
            half8 f[8];
            float elv[8];
#pragma unroll
            for (int q = 0; q < 8; q++) u[q] = adjr[e + q * 2 + half];
#pragma unroll
            for (int q = 0; q < 8; q++)
                f[q] = *(const half8*)&feat[(size_t)u[q] * HID + d0];
#pragma unroll
            for (int q = 0; q < 8; q++)
                elv[q] = (H == 4) ? el[u[q] * 4 + hd] : el[u[q]];
#pragma unroll
            for (int q = 0; q < 8; q++) {
                float sc = elv[q] + er_h;
                sc = (sc > 0.f) ? sc : 0.2f * sc;
                float ex = __expf(sc);
                sl += ex;
#pragma unroll
                for (int j = 0; j < 8; j++) a[j] = fmaf(ex, (float)f[q][j], a[j]);
            }
        }
        for (; e + 8 <= deg; e += 8) {
            int u[4];
            half8 f[4];
            float elv[4];
#pragma unroll
            for (int q = 0; q < 4; q++) u[q] = adjr[e + q * 2 + half];
#pragma unroll
            for (int q = 0; q < 4; q++)
                f[q] = *(const half8*)&feat[(size_t)u[q] * HID + d0];
#pragma unroll
            for (int q = 0; q < 4; q++)
                elv[q] = (H == 4) ? el[u[q] * 4 + hd] : el[u[q]];
#pragma unroll
            for (int q = 0; q < 4; q++) {
                float sc = elv[q] + er_h;
                sc = (sc > 0.f) ? sc : 0.2f * sc;
                float ex = __expf(sc);
                sl += ex;
#pragma unroll
                for (int j = 0; j < 8; j++) a[j] = fmaf(ex, (float)f[q][j], a[j]);
            }
        }
        for (; e < deg; e += 2) {
            int ee = e + half;
            bool act = ee < deg;
            int es = act ? ee : (deg - 1);
            int u = adjr[es];
            float elvq = (H == 4) ? el[u * 4 + hd] : el[u];
            half8 f = *(const half8*)&feat[(size_t)u * HID + d0];
            float sc = elvq + er_h;
            sc = (sc > 0.f) ? sc : 0.2f * sc;
            float ex = act ? __expf(sc) : 0.f;
            sl += ex;
#pragma unroll
            for (int j = 0; j < 8; j++) a[j] = fmaf(ex, (float)f[j], a[j]);
        }

#pragma unroll
        for (int j = 0; j < 8; j++) a[j] += __shfl_xor(a[j], 32);
        sl += __shfl_xor(sl, 32);
        float inv = 1.f / sl;

#pragma unroll
        for (int j = 0; j < 8; j++) {
            o[j] = fmaf(a[j], inv, bias[d0 + j]);
            if (RELU) o[j] = fmaxf(o[j], 0.f);
        }
    } else {
#pragma unroll
        for (int j = 0; j < 8; j++) {
            o[j] = bias[d0 + j];
            if (RELU) o[j] = fmaxf(o[j], 0.f);
        }
    }

    if (half == 0) {
        size_t base = (size_t)v * HID + d0;
        if (WMODE == 0) {
            *(float4*)&outf[base] = make_float4(o[0], o[1], o[2], o[3]);
            *(float4*)&outf[base + 4] = make_float4(o[4], o[5], o[6], o[7]);
        } else {
            half8 ha;
#pragma unroll
            for (int j = 0; j < 8; j++) ha[j] = (_Float16)o[j];
            *(half8*)&oa[base] = ha;
        }
    }
}

// ---------------- launch ----------------

extern "C" void kernel_launch(void* const* d_in, const int* in_sizes, int n_in,
                              void* d_out, int out_size, void* d_ws, size_t ws_size,
                              hipStream_t stream) {
    const float* feats = (const float*)d_in[0];
    const int* src = (const int*)d_in[1];
    const int* dst = (const int*)d_in[2];
    const float* W0 = (const float*)d_in[3];
    const float* al0 = (const float*)d_in[4];
    const float* ar0 = (const float*)d_in[5];
    const float* b0 = (const float*)d_in[6];
    const float* W1 = (const float*)d_in[7];
    const float* al1 = (const float*)d_in[8];
    const float* ar1 = (const float*)d_in[9];
    const float* b1 = (const float*)d_in[10];
    const float* W2 = (const float*)d_in[11];
    const float* al2 = (const float*)d_in[12];
    const float* ar2 = (const float*)d_in[13];
    const float* b2 = (const float*)d_in[14];
    float* out = (float*)d_out;

    const int IN_DIM = 512;
    const int N = in_sizes[0] / IN_DIM;   // 50000
    const int E = in_sizes[1];            // 800000

    char* ws = (char*)d_ws;
    size_t off = 0;
    auto alloc = [&](size_t bytes) -> void* {
        void* p = ws + off;
        off = (off + bytes + 255) & ~(size_t)255;
        return p;
    };
    _Float16* featbuf = (_Float16*)alloc((size_t)N * HID * sizeof(_Float16));  // 25.6 MB
    _Float16* featA = (_Float16*)alloc((size_t)N * HID * sizeof(_Float16));    // 25.6 MB
    float* el = (float*)alloc((size_t)N * 4 * sizeof(float));
    float* er = (float*)alloc((size_t)N * 4 * sizeof(float));
    int* cnt = (int*)alloc((size_t)N * sizeof(int));
    int* rowptr = (int*)alloc((size_t)(N + 1) * sizeof(int));
    int* cursor = (int*)alloc((size_t)N * sizeof(int));
    int* adj = (int*)alloc((size_t)E * sizeof(int));
    int nscanb = (N + 255) / 256;
    int* bsum = (int*)alloc((size_t)nscanb * sizeof(int));
    int* boff = (int*)alloc((size_t)nscanb * sizeof(int));
    _Float16* Bht0 = (_Float16*)alloc((size_t)512 * HID * sizeof(_Float16));
    _Float16* Blt0 = (_Float16*)alloc((size_t)512 * HID * sizeof(_Float16));
    _Float16* Bht1 = (_Float16*)alloc((size_t)256 * HID * sizeof(_Float16));
    _Float16* Blt1 = (_Float16*)alloc((size_t)256 * HID * sizeof(_Float16));
    _Float16* Bht2 = (_Float16*)alloc((size_t)256 * HID * sizeof(_Float16));
    _Float16* Blt2 = (_Float16*)alloc((size_t)256 * HID * sizeof(_Float16));
    (void)ws_size;

    // CSR build
    hipMemsetAsync(cnt, 0, (size_t)N * sizeof(int), stream);
    hist_kernel<<<(E + 255) / 256, 256, 0, stream>>>(dst, cnt, E);
    scan1_kernel<<<nscanb, 256, 0, stream>>>(cnt, bsum, N);
    scan2_kernel<<<1, 256, 0, stream>>>(bsum, boff, nscanb);
    scan3_kernel<<<nscanb, 256, 0, stream>>>(cnt, boff, rowptr, cursor, N);
    fill_kernel<<<(E + 255) / 256, 256, 0, stream>>>(src, dst, cursor, adj, E);

    dim3 ggrid128(HID / 128, (N + 127) / 128);
    int aggb = (N + 3) / 4;

    // weights -> transposed fp16 hi/lo
    splitT_all_kernel<<<(512 * 256 + 2 * 256 * 256) / 256, 256, 0, stream>>>(
        W0, W1, W2, Bht0, Blt0, Bht1, Blt1, Bht2, Blt2);

    // layer 0: fp16 GEMM (A split from fp32 in-kernel), agg -> fp16 A-table
    gemm_f16_kernel<true><<<ggrid128, 256, 0, stream>>>(
        feats, nullptr, Bht0, Blt0, featbuf, al0, ar0, el, er, N, 512, 4);
    agg_tpl<4, true, 2><<<aggb, 256, 0, stream>>>(
        featbuf, el, er, rowptr, adj, b0, nullptr, featA, N);

    // layer 1: fp16 GEMM, agg -> fp16 A-table (featA reused; L1 GEMM done)
    gemm_f16_kernel<false><<<ggrid128, 256, 0, stream>>>(
        nullptr, featA, Bht1, Blt1, featbuf, al1, ar1, el, er, N, 256, 4);
    agg_tpl<4, true, 2><<<aggb, 256, 0, stream>>>(
        featbuf, el, er, rowptr, adj, b1, nullptr, featA, N);

    // layer 2: fp16 GEMM (elr via atomics -> zero el/er first)
    hipMemsetAsync(el, 0, (size_t)N * 8 * sizeof(float), stream);  // el+er contiguous
    gemm_f16_kernel<false><<<ggrid128, 256, 0, stream>>>(
        nullptr, featA, Bht2, Blt2, featbuf, al2, ar2, el, er, N, 256, 1);
    agg_tpl<1, false, 0><<<aggb, 256, 0, stream>>>(
        featbuf, el, er, rowptr, adj, b2, out, nullptr, N);
}

// Round 11
// 573.670 us; speedup vs baseline: 1.0710x; 1.0087x over previous
//
#include <hip/hip_runtime.h>
#include <hip/hip_bf16.h>
#include <math.h>

// ---------------------------------------------------------------------------
// GAT 3-layer forward.
//  - GEMMs: fp16 MFMA, BK=64 (half the barriers of BK=32), single-buffered
//    XOR-swizzled LDS (rows 128B: slot ^= row&7 on 16B slots; both-sides
//    construction: pre-swizzled global source for linear global_load_lds,
//    matching XOR on ds_read / SPLITA ds_write).
//    L0/L1: B single fp16 (W err 2^-11, same order as A err, measured-free
//    class). L2: B fp16-split hi/lo (output-layer accuracy hedge).
//    L0 converts fp32 A to fp16 in registers during staging (SPLITA).
//    elr fused in GEMM epilogue (H=1 via atomics for L2).
//  - agg: wave-per-node, single pass, deferred softmax norm; one fp16 feat
//    table between layers.
//  (Resubmission of R10 source: bench infra failed; audit found no OOB /
//   swizzle / occupancy fault in the kernel.)
// ---------------------------------------------------------------------------

#define HID 256

typedef __attribute__((ext_vector_type(8))) _Float16 half8;
typedef __attribute__((ext_vector_type(4))) float floatx4;

__device__ __forceinline__ void gl_lds16(const void* g, void* l) {
    __builtin_amdgcn_global_load_lds(
        (const __attribute__((address_space(1))) void*)g,
        (__attribute__((address_space(3))) void*)l, 16, 0, 0);
}

// ---------------- CSR build ----------------

__global__ void hist_kernel(const int* __restrict__ dst, int* __restrict__ cnt, int E) {
    int e = blockIdx.x * blockDim.x + threadIdx.x;
    if (e < E) atomicAdd(&cnt[dst[e]], 1);
}

__global__ __launch_bounds__(256) void scan1_kernel(const int* __restrict__ cnt,
                                                    int* __restrict__ bsum, int n) {
    __shared__ int w[4];
    int t = threadIdx.x;
    int i = blockIdx.x * 256 + t;
    int c = (i < n) ? cnt[i] : 0;
    int acc = c;
#pragma unroll
    for (int off = 32; off > 0; off >>= 1) acc += __shfl_xor(acc, off);
    if ((t & 63) == 0) w[t >> 6] = acc;
    __syncthreads();
    if (t == 0) bsum[blockIdx.x] = w[0] + w[1] + w[2] + w[3];
}

__global__ __launch_bounds__(256) void scan2_kernel(const int* __restrict__ bsum,
                                                    int* __restrict__ boff, int nb) {
    __shared__ int buf[256];
    int t = threadIdx.x;
    int v = (t < nb) ? bsum[t] : 0;
    buf[t] = v;
    __syncthreads();
    for (int off = 1; off < 256; off <<= 1) {
        int x = (t >= off) ? buf[t - off] : 0;
        __syncthreads();
        buf[t] += x;
        __syncthreads();
    }
    if (t < nb) boff[t] = buf[t] - v;
}

__global__ __launch_bounds__(256) void scan3_kernel(const int* __restrict__ cnt,
                                                    const int* __restrict__ boff,
                                                    int* __restrict__ rowptr,
                                                    int* __restrict__ cursor, int n) {
    __shared__ int buf[256];
    int t = threadIdx.x;
    int i = blockIdx.x * 256 + t;
    int c = (i < n) ? cnt[i] : 0;
    buf[t] = c;
    __syncthreads();
    for (int off = 1; off < 256; off <<= 1) {
        int x = (t >= off) ? buf[t - off] : 0;
        __syncthreads();
        buf[t] += x;
        __syncthreads();
    }
    int start = boff[blockIdx.x] + buf[t] - c;
    if (i < n) {
        rowptr[i] = start;
        cursor[i] = start;
        if (i == n - 1) rowptr[n] = start + c;
    }
}

__global__ void fill_kernel(const int* __restrict__ src, const int* __restrict__ dst,
                            int* __restrict__ cursor, int* __restrict__ adj, int E) {
    int e = blockIdx.x * blockDim.x + threadIdx.x;
    if (e < E) {
        int d = dst[e];
        int pos = atomicAdd(&cursor[d], 1);
        adj[pos] = src[e];
    }
}

// ---------- weights: all -> transposed fp16 hi/lo ----------

__device__ __forceinline__ void splitT_f16(const float* W, _Float16* ht, _Float16* lt,
                                           int idx, int K) {
    int k = idx >> 8, n = idx & 255;
    float v = W[idx];
    _Float16 h = (_Float16)v;
    ht[(size_t)n * K + k] = h;
    lt[(size_t)n * K + k] = (_Float16)(v - (float)h);
}

__global__ __launch_bounds__(256) void splitT_all_kernel(
    const float* __restrict__ W0, const float* __restrict__ W1,
    const float* __restrict__ W2, _Float16* h0, _Float16* l0, _Float16* h1,
    _Float16* l1, _Float16* h2, _Float16* l2) {
    int i = blockIdx.x * 256 + threadIdx.x;
    const int n0 = 512 * 256, n1 = 256 * 256;
    if (i < n0) splitT_f16(W0, h0, l0, i, 512);
    else if (i < n0 + n1) splitT_f16(W1, h1, l1, i - n0, 256);
    else if (i < n0 + 2 * n1) splitT_f16(W2, h2, l2, i - n0 - n1, 256);
}

// ---------------- fp16 MFMA GEMM, BK=64 + fused elr ----------------
// C[M,256](fp16) = A(fp16) @ B(fp16[+Bl if SPLITB]).
// Tile 128x128, BK=64. LDS rows are 128B (64 fp16) = all 32 banks; swizzle:
// 16B slot index ^= (row&7). gl_lds keeps linear dest; global source slot is
// pre-swizzled (constant per thread). ds_read/ds_write use the matching XOR.
// SPLITA: A fp32 -> fp16 in registers during staging.
// H==4: direct elr store; H==1: atomic accumulate (el/er pre-zeroed).

template <bool SPLITA, bool SPLITB>
__global__ __launch_bounds__(256, 2) void gemm_f16_kernel(
    const float* __restrict__ Af, const _Float16* __restrict__ A16,
    const _Float16* __restrict__ Bht, const _Float16* __restrict__ Blt,
    _Float16* __restrict__ C, const float* __restrict__ al,
    const float* __restrict__ ar, float* __restrict__ el,
    float* __restrict__ er, int M, int K, int H) {
    __shared__ _Float16 sA[128 * 64];                     // 16 KB
    __shared__ _Float16 sB[128 * 64];                     // 16 KB
    __shared__ _Float16 sBl[SPLITB ? 128 * 64 : 8];       // 16 KB (L2 only)

    int t = threadIdx.x;
    int wave = t >> 6, lane = t & 63;
    int wr = wave >> 1, wc = wave & 1;
    int quad = lane >> 4, m16 = lane & 15;

    int rowA0 = blockIdx.y * 128;
    int rowB0 = blockIdx.x * 128;

    // gl_lds staging: thread t stages 4 chunks c = t + 256*i (16B each).
    // chunk c -> (row c>>3, slot c&7); slot bits unaffected by i, row += 32*i.
    // global source slot pre-swizzled: gslot = (t&7) ^ ((t>>3)&7)  (const).
    int srow0 = t >> 3;                      // rows srow0 + 32*i
    int gslot = ((t & 7) ^ ((t >> 3) & 7)) * 8;  // element offset of 16B chunk
    int ldso = t * 8;                        // linear LDS dest (elems), +2048*i

    // SPLITA reg staging: thread t -> row t>>1, cols (t&1)*32 .. +32
    int arow = t >> 1;
    int akb = (t & 1) * 32;
    int arsw = arow & 7;

    size_t aoff[4], boff[4];
#pragma unroll
    for (int i = 0; i < 4; i++) {
        int r = srow0 + 32 * i;
        boff[i] = (size_t)(rowB0 + r) * K + gslot;
        if (!SPLITA) aoff[i] = (size_t)min(rowA0 + r, M - 1) * K + gslot;
    }
    size_t af0 = 0;
    if (SPLITA) af0 = (size_t)min(rowA0 + arow, M - 1) * K + akb;

    int rswz = m16 & 7;  // frag-read row-swizzle (row&7 == m16&7)

    floatx4 acc[4][4];
    floatx4 z = {0.f, 0.f, 0.f, 0.f};
#pragma unroll
    for (int i = 0; i < 4; i++)
#pragma unroll
        for (int j = 0; j < 4; j++) acc[i][j] = z;

    int nk = K >> 6;
    for (int kt = 0; kt < nk; kt++) {
        int k0 = kt << 6;
        // ---- stage B (and A) via gl_lds; SPLITA A via registers ----
#pragma unroll
        for (int i = 0; i < 4; i++)
            gl_lds16(Bht + boff[i] + k0, &sB[ldso + 2048 * i]);
        if (SPLITB) {
#pragma unroll
            for (int i = 0; i < 4; i++)
                gl_lds16(Blt + boff[i] + k0, &sBl[ldso + 2048 * i]);
        }
        if (SPLITA) {
            const float4* ap = (const float4*)(Af + af0 + k0);
#pragma unroll
            for (int j = 0; j < 4; j++) {
                float4 a = ap[2 * j];
                float4 b = ap[2 * j + 1];
                half8 h;
                h[0] = (_Float16)a.x; h[1] = (_Float16)a.y;
                h[2] = (_Float16)a.z; h[3] = (_Float16)a.w;
                h[4] = (_Float16)b.x; h[5] = (_Float16)b.y;
                h[6] = (_Float16)b.z; h[7] = (_Float16)b.w;
                int slot = (((t & 1) * 4 + j) ^ arsw);
                *(half8*)&sA[arow * 64 + slot * 8] = h;
            }
        } else {
#pragma unroll
            for (int i = 0; i < 4; i++)
                gl_lds16(A16 + aoff[i] + k0, &sA[ldso + 2048 * i]);
        }
        __syncthreads();

        // ---- 2 sub-K steps of 32 ----
#pragma unroll
        for (int kk = 0; kk < 2; kk++) {
            half8 fa[4], fb[4], fbl[4];
#pragma unroll
            for (int i = 0; i < 4; i++) {
                int row = wr * 64 + i * 16 + m16;
                int slot = ((kk * 4 + quad) ^ rswz);
                fa[i] = *(const half8*)&sA[row * 64 + slot * 8];
            }
#pragma unroll
            for (int j = 0; j < 4; j++) {
                int row = wc * 64 + j * 16 + m16;
                int slot = ((kk * 4 + quad) ^ rswz);
                fb[j] = *(const half8*)&sB[row * 64 + slot * 8];
                if (SPLITB) fbl[j] = *(const half8*)&sBl[row * 64 + slot * 8];
            }
#pragma unroll
            for (int i = 0; i < 4; i++)
#pragma unroll
                for (int j = 0; j < 4; j++) {
                    acc[i][j] = __builtin_amdgcn_mfma_f32_16x16x32_f16(fa[i], fb[j], acc[i][j], 0, 0, 0);
                    if (SPLITB)
                        acc[i][j] = __builtin_amdgcn_mfma_f32_16x16x32_f16(fa[i], fbl[j], acc[i][j], 0, 0, 0);
                }
        }
        __syncthreads();
    }

    // C store (C/D layout: col = m16, row = quad*4 + reg)
#pragma unroll
    for (int i = 0; i < 4; i++) {
        int rowb = rowA0 + wr * 64 + i * 16 + quad * 4;
#pragma unroll
        for (int j = 0; j < 4; j++) {
            int col = rowB0 + wc * 64 + j * 16 + m16;
#pragma unroll
            for (int r = 0; r < 4; r++) {
                int row = rowb + r;
                if (row < M) C[(size_t)row * HID + col] = (_Float16)acc[i][j][r];
            }
        }
    }

    // fused elr
    float alv[4], arv[4];
#pragma unroll
    for (int j = 0; j < 4; j++) {
        int col = rowB0 + wc * 64 + j * 16 + m16;
        alv[j] = al[col];
        arv[j] = ar[col];
    }
    int h = ((rowB0 + wc * 64) >> 6) & (H - 1);
#pragma unroll
    for (int i = 0; i < 4; i++) {
        int rowb = rowA0 + wr * 64 + i * 16 + quad * 4;
#pragma unroll
        for (int r = 0; r < 4; r++) {
            float pe = acc[i][0][r] * alv[0] + acc[i][1][r] * alv[1] +
                       acc[i][2][r] * alv[2] + acc[i][3][r] * alv[3];
            float pr = acc[i][0][r] * arv[0] + acc[i][1][r] * arv[1] +
                       acc[i][2][r] * arv[2] + acc[i][3][r] * arv[3];
#pragma unroll
            for (int off = 1; off < 16; off <<= 1) {
                pe += __shfl_xor(pe, off);
                pr += __shfl_xor(pr, off);
            }
            int row = rowb + r;
            if (m16 == 0 && row < M) {
                if (H == 4) {
                    el[row * 4 + h] = pe;
                    er[row * 4 + h] = pr;
                } else {
                    atomicAdd(&el[row], pe);
                    atomicAdd(&er[row], pr);
                }
            }
        }
    }
}

// ---------------- agg: wave-per-node, single pass, deferred softmax norm ----
// WMODE: 0 = fp32 out, 2 = fp16 single table.

template <int H, bool RELU, int WMODE>
__global__ __launch_bounds__(256) void agg_tpl(
    const _Float16* __restrict__ feat, const float* __restrict__ el,
    const float* __restrict__ er, const int* __restrict__ rowptr,
    const int* __restrict__ adj, const float* __restrict__ bias,
    float* __restrict__ outf, _Float16* __restrict__ oa, int N) {
    int wave = threadIdx.x >> 6, lane = threadIdx.x & 63;
    int v = blockIdx.x * 4 + wave;
    if (v >= N) return;
    int row0 = rowptr[v];
    int deg = rowptr[v + 1] - row0;

    int l32 = lane & 31;
    int half = lane >> 5;
    int hd = (H == 4) ? (l32 >> 3) : 0;
    int d0 = l32 * 8;

    float o[8];
    if (deg > 0) {
        float er_h = (H == 4) ? er[v * 4 + hd] : er[v];
        const int* adjr = adj + row0;

        float a[8];
#pragma unroll
        for (int j = 0; j < 8; j++) a[j] = 0.f;
        float sl = 0.f;

        int e = 0;
        for (; e + 16 <= deg; e += 16) {
            int u[8];
            half8 f[8];
            float elv[8];
#pragma unroll
            for (int q = 0; q < 8; q++) u[q] = adjr[e + q * 2 + half];
#pragma unroll
            for (int q = 0; q < 8; q++)
                f[q] = *(const half8*)&feat[(size_t)u[q] * HID + d0];
#pragma unroll
            for (int q = 0; q < 8; q++)
                elv[q] = (H == 4) ? el[u[q] * 4 + hd] : el[u[q]];
#pragma unroll
            for (int q = 0; q < 8; q++) {
                float sc = elv[q] + er_h;
                sc = (sc > 0.f) ? sc : 0.2f * sc;
                float ex = __expf(sc);
                sl += ex;
#pragma unroll
                for (int j = 0; j < 8; j++) a[j] = fmaf(ex, (float)f[q][j], a[j]);
            }
        }
        for (; e + 8 <= deg; e += 8) {
            int u[4];
            half8 f[4];
            float elv[4];
#pragma unroll
            for (int q = 0; q < 4; q++) u[q] = adjr[e + q * 2 + half];
#pragma unroll
            for (int q = 0; q < 4; q++)
                f[q] = *(const half8*)&feat[(size_t)u[q] * HID + d0];
#pragma unroll
            for (int q = 0; q < 4; q++)
                elv[q] = (H == 4) ? el[u[q] * 4 + hd] : el[u[q]];
#pragma unroll
            for (int q = 0; q < 4; q++) {
                float sc = elv[q] + er_h;
                sc = (sc > 0.f) ? sc : 0.2f * sc;
                float ex = __expf(sc);
                sl += ex;
#pragma unroll
                for (int j = 0; j < 8; j++) a[j] = fmaf(ex, (float)f[q][j], a[j]);
            }
        }
        for (; e < deg; e += 2) {
            int ee = e + half;
            bool act = ee < deg;
            int es = act ? ee : (deg - 1);
            int u = adjr[es];
            float elvq = (H == 4) ? el[u * 4 + hd] : el[u];
            half8 f = *(const half8*)&feat[(size_t)u * HID + d0];
            float sc = elvq + er_h;
            sc = (sc > 0.f) ? sc : 0.2f * sc;
            float ex = act ? __expf(sc) : 0.f;
            sl += ex;
#pragma unroll
            for (int j = 0; j < 8; j++) a[j] = fmaf(ex, (float)f[j], a[j]);
        }

#pragma unroll
        for (int j = 0; j < 8; j++) a[j] += __shfl_xor(a[j], 32);
        sl += __shfl_xor(sl, 32);
        float inv = 1.f / sl;

#pragma unroll
        for (int j = 0; j < 8; j++) {
            o[j] = fmaf(a[j], inv, bias[d0 + j]);
            if (RELU) o[j] = fmaxf(o[j], 0.f);
        }
    } else {
#pragma unroll
        for (int j = 0; j < 8; j++) {
            o[j] = bias[d0 + j];
            if (RELU) o[j] = fmaxf(o[j], 0.f);
        }
    }

    if (half == 0) {
        size_t base = (size_t)v * HID + d0;
        if (WMODE == 0) {
            *(float4*)&outf[base] = make_float4(o[0], o[1], o[2], o[3]);
            *(float4*)&outf[base + 4] = make_float4(o[4], o[5], o[6], o[7]);
        } else {
            half8 ha;
#pragma unroll
            for (int j = 0; j < 8; j++) ha[j] = (_Float16)o[j];
            *(half8*)&oa[base] = ha;
        }
    }
}

// ---------------- launch ----------------

extern "C" void kernel_launch(void* const* d_in, const int* in_sizes, int n_in,
                              void* d_out, int out_size, void* d_ws, size_t ws_size,
                              hipStream_t stream) {
    const float* feats = (const float*)d_in[0];
    const int* src = (const int*)d_in[1];
    const int* dst = (const int*)d_in[2];
    const float* W0 = (const float*)d_in[3];
    const float* al0 = (const float*)d_in[4];
    const float* ar0 = (const float*)d_in[5];
    const float* b0 = (const float*)d_in[6];
    const float* W1 = (const float*)d_in[7];
    const float* al1 = (const float*)d_in[8];
    const float* ar1 = (const float*)d_in[9];
    const float* b1 = (const float*)d_in[10];
    const float* W2 = (const float*)d_in[11];
    const float* al2 = (const float*)d_in[12];
    const float* ar2 = (const float*)d_in[13];
    const float* b2 = (const float*)d_in[14];
    float* out = (float*)d_out;

    const int IN_DIM = 512;
    const int N = in_sizes[0] / IN_DIM;   // 50000
    const int E = in_sizes[1];            // 800000

    char* ws = (char*)d_ws;
    size_t off = 0;
    auto alloc = [&](size_t bytes) -> void* {
        void* p = ws + off;
        off = (off + bytes + 255) & ~(size_t)255;
        return p;
    };
    _Float16* featbuf = (_Float16*)alloc((size_t)N * HID * sizeof(_Float16));  // 25.6 MB
    _Float16* featA = (_Float16*)alloc((size_t)N * HID * sizeof(_Float16));    // 25.6 MB
    float* el = (float*)alloc((size_t)N * 4 * sizeof(float));
    float* er = (float*)alloc((size_t)N * 4 * sizeof(float));
    int* cnt = (int*)alloc((size_t)N * sizeof(int));
    int* rowptr = (int*)alloc((size_t)(N + 1) * sizeof(int));
    int* cursor = (int*)alloc((size_t)N * sizeof(int));
    int* adj = (int*)alloc((size_t)E * sizeof(int));
    int nscanb = (N + 255) / 256;
    int* bsum = (int*)alloc((size_t)nscanb * sizeof(int));
    int* boff = (int*)alloc((size_t)nscanb * sizeof(int));
    _Float16* Bht0 = (_Float16*)alloc((size_t)512 * HID * sizeof(_Float16));
    _Float16* Blt0 = (_Float16*)alloc((size_t)512 * HID * sizeof(_Float16));
    _Float16* Bht1 = (_Float16*)alloc((size_t)256 * HID * sizeof(_Float16));
    _Float16* Blt1 = (_Float16*)alloc((size_t)256 * HID * sizeof(_Float16));
    _Float16* Bht2 = (_Float16*)alloc((size_t)256 * HID * sizeof(_Float16));
    _Float16* Blt2 = (_Float16*)alloc((size_t)256 * HID * sizeof(_Float16));
    (void)ws_size;

    // CSR build
    hipMemsetAsync(cnt, 0, (size_t)N * sizeof(int), stream);
    hist_kernel<<<(E + 255) / 256, 256, 0, stream>>>(dst, cnt, E);
    scan1_kernel<<<nscanb, 256, 0, stream>>>(cnt, bsum, N);
    scan2_kernel<<<1, 256, 0, stream>>>(bsum, boff, nscanb);
    scan3_kernel<<<nscanb, 256, 0, stream>>>(cnt, boff, rowptr, cursor, N);
    fill_kernel<<<(E + 255) / 256, 256, 0, stream>>>(src, dst, cursor, adj, E);

    dim3 ggrid128(HID / 128, (N + 127) / 128);
    int aggb = (N + 3) / 4;

    // weights -> transposed fp16 hi/lo
    splitT_all_kernel<<<(512 * 256 + 2 * 256 * 256) / 256, 256, 0, stream>>>(
        W0, W1, W2, Bht0, Blt0, Bht1, Blt1, Bht2, Blt2);

    // layer 0: SPLITA, B single fp16
    gemm_f16_kernel<true, false><<<ggrid128, 256, 0, stream>>>(
        feats, nullptr, Bht0, nullptr, featbuf, al0, ar0, el, er, N, 512, 4);
    agg_tpl<4, true, 2><<<aggb, 256, 0, stream>>>(
        featbuf, el, er, rowptr, adj, b0, nullptr, featA, N);

    // layer 1: B single fp16
    gemm_f16_kernel<false, false><<<ggrid128, 256, 0, stream>>>(
        nullptr, featA, Bht1, nullptr, featbuf, al1, ar1, el, er, N, 256, 4);
    agg_tpl<4, true, 2><<<aggb, 256, 0, stream>>>(
        featbuf, el, er, rowptr, adj, b1, nullptr, featA, N);

    // layer 2: B fp16-split (hedge), elr via atomics -> zero el/er first
    hipMemsetAsync(el, 0, (size_t)N * 8 * sizeof(float), stream);  // el+er contiguous
    gemm_f16_kernel<false, true><<<ggrid128, 256, 0, stream>>>(
        nullptr, featA, Bht2, Blt2, featbuf, al2, ar2, el, er, N, 256, 1);
    agg_tpl<1, false, 0><<<aggb, 256, 0, stream>>>(
        featbuf, el, er, rowptr, adj, b2, out, nullptr, N);
}